// Round 4
// baseline (512.713 us; speedup 1.0000x reference)
//
#include <hip/hip_runtime.h>

#define NN 50000
#define NHEADS 16
#define NGRAPH 128
#define NEDGE 800000
#define NEP (NEDGE + NN)

typedef float4 f4;
typedef __attribute__((ext_vector_type(4))) float f32x4;
typedef __attribute__((ext_vector_type(8))) short s8;   // 8 bf16 (4 VGPRs)

__device__ inline unsigned short f2b(float f) {
  union { float f; unsigned u; } v; v.f = f;
  unsigned r = v.u + 0x7FFFu + ((v.u >> 16) & 1u);   // RNE
  return (unsigned short)(r >> 16);
}
__device__ inline float b2f(unsigned u16) {          // low 16 bits = bf16
  union { unsigned u; float f; } v; v.u = u16 << 16;
  return v.f;
}

// ---------------- CSR build ----------------

__global__ __launch_bounds__(256) void k_hist(const int* __restrict__ ei, int* __restrict__ counts) {
  int i = blockIdx.x * 256 + threadIdx.x;
  if (i >= NEP) return;
  int d = (i < NEDGE) ? ei[NEDGE + i] : (i - NEDGE);
  atomicAdd(&counts[d], 1);
}

__global__ __launch_bounds__(256) void k_scan1(const int* __restrict__ counts, int* __restrict__ row_off, int* __restrict__ blk_tot) {
  __shared__ int buf[256];
  int t = threadIdx.x;
  int i = blockIdx.x * 256 + t;
  int v = (i < NN) ? counts[i] : 0;
  buf[t] = v;
  __syncthreads();
  for (int off = 1; off < 256; off <<= 1) {
    int y = (t >= off) ? buf[t - off] : 0;
    __syncthreads();
    buf[t] += y;
    __syncthreads();
  }
  if (i < NN) row_off[i] = buf[t] - v;
  if (t == 255) blk_tot[blockIdx.x] = buf[255];
}

__global__ __launch_bounds__(256) void k_scan2(const int* __restrict__ blk_tot, int* __restrict__ blk_off, int* __restrict__ row_off, int nb) {
  __shared__ int buf[256];
  int t = threadIdx.x;
  int v = (t < nb) ? blk_tot[t] : 0;
  buf[t] = v;
  __syncthreads();
  for (int off = 1; off < 256; off <<= 1) {
    int y = (t >= off) ? buf[t - off] : 0;
    __syncthreads();
    buf[t] += y;
    __syncthreads();
  }
  if (t < nb) blk_off[t] = buf[t] - v;
  if (t == 255) row_off[NN] = buf[255];
}

__global__ __launch_bounds__(256) void k_scan3(int* __restrict__ row_off, const int* __restrict__ blk_off) {
  int i = blockIdx.x * 256 + threadIdx.x;
  if (i < NN) row_off[i] += blk_off[blockIdx.x];
}

__global__ __launch_bounds__(256) void k_scatter(const int* __restrict__ ei, int* __restrict__ cursor, int* __restrict__ col) {
  int i = blockIdx.x * 256 + threadIdx.x;
  if (i >= NEP) return;
  int s, d;
  if (i < NEDGE) { s = ei[i]; d = ei[NEDGE + i]; }
  else { s = d = i - NEDGE; }
  int pos = atomicAdd(&cursor[d], 1);
  col[pos] = s;
}

// ---------------- fp32 -> bf16 cast (x -> Xb) ----------------

__global__ __launch_bounds__(256) void k_cast(const float* __restrict__ X, unsigned short* __restrict__ Xb, int total8) {
  int i = blockIdx.x * 256 + threadIdx.x;      // 8 elems per thread
  if (i >= total8) return;
  const f4* X4 = (const f4*)X;
  f4 a = X4[2 * i], b = X4[2 * i + 1];
  uint4 o;
  o.x = (unsigned)f2b(a.x) | ((unsigned)f2b(a.y) << 16);
  o.y = (unsigned)f2b(a.z) | ((unsigned)f2b(a.w) << 16);
  o.z = (unsigned)f2b(b.x) | ((unsigned)f2b(b.y) << 16);
  o.w = (unsigned)f2b(b.z) | ((unsigned)f2b(b.w) << 16);
  ((uint4*)Xb)[i] = o;
}

// ---------------- W -> W^T bf16 for all 3 layers ----------------

__global__ __launch_bounds__(256) void k_wt(const float* __restrict__ W0, const float* __restrict__ W1, const float* __restrict__ W2,
                                            unsigned short* __restrict__ T0, unsigned short* __restrict__ T1, unsigned short* __restrict__ T2) {
  int idx = blockIdx.x * 256 + threadIdx.x;    // 3 * 16384
  int L = idx >> 14, r = idx & 16383;
  int n = r >> 7, k = r & 127;
  const float* W = (L == 0) ? W0 : (L == 1) ? W1 : W2;
  unsigned short* T = (L == 0) ? T0 : (L == 1) ? T1 : T2;
  T[n * 128 + k] = f2b(W[k * 128 + n]);
}

// ---------------- GEMM: Hb = bf16( Xb @ W )  via MFMA, no LDS ----------------

__global__ __launch_bounds__(256) void k_gemm(const unsigned short* __restrict__ Xb, const unsigned short* __restrict__ Wt,
                                              unsigned short* __restrict__ Hb) {
  int w = threadIdx.x >> 6, l = threadIdx.x & 63;
  int r0 = blockIdx.x * 128 + w * 32;          // this wave: rows r0..r0+31, all 128 cols
  int lr = l & 15, lg = l >> 4;
  f32x4 acc[2][8];
#pragma unroll
  for (int m = 0; m < 2; ++m)
#pragma unroll
    for (int n = 0; n < 8; ++n) acc[m][n] = (f32x4){0.f, 0.f, 0.f, 0.f};

#pragma unroll
  for (int ks = 0; ks < 4; ++ks) {
    int koff = ks * 32 + lg * 8;
    s8 a[2];
#pragma unroll
    for (int m = 0; m < 2; ++m) {
      int row = r0 + m * 16 + lr;
      row = (row < NN) ? row : (NN - 1);
      a[m] = *(const s8*)(Xb + (size_t)row * 128 + koff);
    }
    s8 b[8];
#pragma unroll
    for (int n = 0; n < 8; ++n)
      b[n] = *(const s8*)(Wt + (size_t)(n * 16 + lr) * 128 + koff);
#pragma unroll
    for (int m = 0; m < 2; ++m)
#pragma unroll
      for (int n = 0; n < 8; ++n)
        acc[m][n] = __builtin_amdgcn_mfma_f32_16x16x32_bf16(a[m], b[n], acc[m][n], 0, 0, 0);
  }

  // C/D layout: col = lane&15, row = (lane>>4)*4 + reg   [verified m89/m91]
#pragma unroll
  for (int m = 0; m < 2; ++m) {
    int rowb = r0 + m * 16 + lg * 4;
#pragma unroll
    for (int n = 0; n < 8; ++n) {
      int colb = n * 16 + lr;
#pragma unroll
      for (int reg = 0; reg < 4; ++reg) {
        int row = rowb + reg;
        if (row < NN) Hb[(size_t)row * 128 + colb] = f2b(acc[m][n][reg]);
      }
    }
  }
}

// ---------------- attention coefficients from bf16 H ----------------
// As stored bf16 (gathered per-edge in k_agg); Ad stays fp32 (read per-node).

__global__ __launch_bounds__(256) void k_coef(const unsigned short* __restrict__ Hb, const float* __restrict__ asrc,
                                              const float* __restrict__ adst, unsigned short* __restrict__ Asb, float* __restrict__ Ad) {
  int idx = blockIdx.x * 256 + threadIdx.x;
  if (idx >= NN * NHEADS) return;
  int n = idx >> 4, hd = idx & 15;
  uint4 hv = *(const uint4*)(Hb + (size_t)n * 128 + hd * 8);
  float h0 = b2f(hv.x & 0xffff), h1 = b2f(hv.x >> 16);
  float h2 = b2f(hv.y & 0xffff), h3 = b2f(hv.y >> 16);
  float h4 = b2f(hv.z & 0xffff), h5 = b2f(hv.z >> 16);
  float h6 = b2f(hv.w & 0xffff), h7 = b2f(hv.w >> 16);
  const f4* s4 = (const f4*)(asrc + hd * 8);
  const f4* d4 = (const f4*)(adst + hd * 8);
  f4 sa = s4[0], sb = s4[1], da = d4[0], db = d4[1];
  float as_v = h0 * sa.x + h1 * sa.y + h2 * sa.z + h3 * sa.w + h4 * sb.x + h5 * sb.y + h6 * sb.z + h7 * sb.w;
  float ad_v = h0 * da.x + h1 * da.y + h2 * da.z + h3 * da.w + h4 * db.x + h5 * db.y + h6 * db.z + h7 * db.w;
  Asb[idx] = f2b(as_v);
  Ad[idx] = ad_v;
}

// ---------------- aggregation: single pass, 8-deep pipelined bf16 gather ----------------
// 32 lanes per node, lane owns channels 4l..4l+3 -> head = l>>1.
// exp without max-shift: softmax shift-invariant, |e| bounded (~3) so no overflow.
// GAT bias dropped: the following BN subtracts the per-channel mean, which absorbs
// any per-channel additive constant exactly.

__global__ __launch_bounds__(256) void k_agg(const unsigned short* __restrict__ Hb, const unsigned short* __restrict__ Asb,
                                             const float* __restrict__ Ad,
                                             const int* __restrict__ row_off, const int* __restrict__ col,
                                             float* __restrict__ V) {
  int node = blockIdx.x * 8 + (threadIdx.x >> 5);   // 6250*8 == 50000 exactly
  int l = threadIdx.x & 31;
  int h = l >> 1;
  int e0 = row_off[node], e1 = row_off[node + 1];
  float adh = Ad[node * 16 + h];
  float den = 0.f;
  f4 acc = make_float4(0.f, 0.f, 0.f, 0.f);
  int j = e0;
  for (; j + 8 <= e1; j += 8) {
    int s0 = col[j],     s1 = col[j + 1], s2 = col[j + 2], s3 = col[j + 3];
    int s4 = col[j + 4], s5 = col[j + 5], s6 = col[j + 6], s7 = col[j + 7];
    float a0 = b2f(Asb[s0 * 16 + h]), a1 = b2f(Asb[s1 * 16 + h]);
    float a2 = b2f(Asb[s2 * 16 + h]), a3 = b2f(Asb[s3 * 16 + h]);
    float a4 = b2f(Asb[s4 * 16 + h]), a5 = b2f(Asb[s5 * 16 + h]);
    float a6 = b2f(Asb[s6 * 16 + h]), a7 = b2f(Asb[s7 * 16 + h]);
    uint2 p0 = *(const uint2*)(Hb + (size_t)s0 * 128 + l * 4);
    uint2 p1 = *(const uint2*)(Hb + (size_t)s1 * 128 + l * 4);
    uint2 p2 = *(const uint2*)(Hb + (size_t)s2 * 128 + l * 4);
    uint2 p3 = *(const uint2*)(Hb + (size_t)s3 * 128 + l * 4);
    uint2 p4 = *(const uint2*)(Hb + (size_t)s4 * 128 + l * 4);
    uint2 p5 = *(const uint2*)(Hb + (size_t)s5 * 128 + l * 4);
    uint2 p6 = *(const uint2*)(Hb + (size_t)s6 * 128 + l * 4);
    uint2 p7 = *(const uint2*)(Hb + (size_t)s7 * 128 + l * 4);
    a0 += adh; a1 += adh; a2 += adh; a3 += adh;
    a4 += adh; a5 += adh; a6 += adh; a7 += adh;
    a0 = (a0 > 0.f) ? a0 : 0.2f * a0;  a1 = (a1 > 0.f) ? a1 : 0.2f * a1;
    a2 = (a2 > 0.f) ? a2 : 0.2f * a2;  a3 = (a3 > 0.f) ? a3 : 0.2f * a3;
    a4 = (a4 > 0.f) ? a4 : 0.2f * a4;  a5 = (a5 > 0.f) ? a5 : 0.2f * a5;
    a6 = (a6 > 0.f) ? a6 : 0.2f * a6;  a7 = (a7 > 0.f) ? a7 : 0.2f * a7;
    float x0 = __expf(a0), x1 = __expf(a1), x2 = __expf(a2), x3 = __expf(a3);
    float x4 = __expf(a4), x5 = __expf(a5), x6 = __expf(a6), x7 = __expf(a7);
    den += ((x0 + x1) + (x2 + x3)) + ((x4 + x5) + (x6 + x7));
    acc.x += x0 * b2f(p0.x & 0xffff) + x1 * b2f(p1.x & 0xffff) + x2 * b2f(p2.x & 0xffff) + x3 * b2f(p3.x & 0xffff)
           + x4 * b2f(p4.x & 0xffff) + x5 * b2f(p5.x & 0xffff) + x6 * b2f(p6.x & 0xffff) + x7 * b2f(p7.x & 0xffff);
    acc.y += x0 * b2f(p0.x >> 16)    + x1 * b2f(p1.x >> 16)    + x2 * b2f(p2.x >> 16)    + x3 * b2f(p3.x >> 16)
           + x4 * b2f(p4.x >> 16)    + x5 * b2f(p5.x >> 16)    + x6 * b2f(p6.x >> 16)    + x7 * b2f(p7.x >> 16);
    acc.z += x0 * b2f(p0.y & 0xffff) + x1 * b2f(p1.y & 0xffff) + x2 * b2f(p2.y & 0xffff) + x3 * b2f(p3.y & 0xffff)
           + x4 * b2f(p4.y & 0xffff) + x5 * b2f(p5.y & 0xffff) + x6 * b2f(p6.y & 0xffff) + x7 * b2f(p7.y & 0xffff);
    acc.w += x0 * b2f(p0.y >> 16)    + x1 * b2f(p1.y >> 16)    + x2 * b2f(p2.y >> 16)    + x3 * b2f(p3.y >> 16)
           + x4 * b2f(p4.y >> 16)    + x5 * b2f(p5.y >> 16)    + x6 * b2f(p6.y >> 16)    + x7 * b2f(p7.y >> 16);
  }
  for (; j + 4 <= e1; j += 4) {
    int s0 = col[j], s1 = col[j + 1], s2 = col[j + 2], s3 = col[j + 3];
    float a0 = b2f(Asb[s0 * 16 + h]), a1 = b2f(Asb[s1 * 16 + h]);
    float a2 = b2f(Asb[s2 * 16 + h]), a3 = b2f(Asb[s3 * 16 + h]);
    uint2 p0 = *(const uint2*)(Hb + (size_t)s0 * 128 + l * 4);
    uint2 p1 = *(const uint2*)(Hb + (size_t)s1 * 128 + l * 4);
    uint2 p2 = *(const uint2*)(Hb + (size_t)s2 * 128 + l * 4);
    uint2 p3 = *(const uint2*)(Hb + (size_t)s3 * 128 + l * 4);
    a0 += adh; a1 += adh; a2 += adh; a3 += adh;
    a0 = (a0 > 0.f) ? a0 : 0.2f * a0;  a1 = (a1 > 0.f) ? a1 : 0.2f * a1;
    a2 = (a2 > 0.f) ? a2 : 0.2f * a2;  a3 = (a3 > 0.f) ? a3 : 0.2f * a3;
    float x0 = __expf(a0), x1 = __expf(a1), x2 = __expf(a2), x3 = __expf(a3);
    den += (x0 + x1) + (x2 + x3);
    acc.x += x0 * b2f(p0.x & 0xffff) + x1 * b2f(p1.x & 0xffff) + x2 * b2f(p2.x & 0xffff) + x3 * b2f(p3.x & 0xffff);
    acc.y += x0 * b2f(p0.x >> 16)    + x1 * b2f(p1.x >> 16)    + x2 * b2f(p2.x >> 16)    + x3 * b2f(p3.x >> 16);
    acc.z += x0 * b2f(p0.y & 0xffff) + x1 * b2f(p1.y & 0xffff) + x2 * b2f(p2.y & 0xffff) + x3 * b2f(p3.y & 0xffff);
    acc.w += x0 * b2f(p0.y >> 16)    + x1 * b2f(p1.y >> 16)    + x2 * b2f(p2.y >> 16)    + x3 * b2f(p3.y >> 16);
  }
  for (; j < e1; ++j) {
    int s0 = col[j];
    float a0 = b2f(Asb[s0 * 16 + h]) + adh;
    uint2 p0 = *(const uint2*)(Hb + (size_t)s0 * 128 + l * 4);
    a0 = (a0 > 0.f) ? a0 : 0.2f * a0;
    float x0 = __expf(a0);
    den += x0;
    acc.x += x0 * b2f(p0.x & 0xffff);
    acc.y += x0 * b2f(p0.x >> 16);
    acc.z += x0 * b2f(p0.y & 0xffff);
    acc.w += x0 * b2f(p0.y >> 16);
  }
  float inv = 1.f / (den + 1e-16f);
  f4 o;
  o.x = acc.x * inv;
  o.y = acc.y * inv;
  o.z = acc.z * inv;
  o.w = acc.w * inv;
  *(f4*)(V + (size_t)node * 128 + l * 4) = o;
}

// ---------------- BatchNorm: atomic-free two-stage reduce ----------------
// Stage 1: 256 blocks x 2 row-streams -> partS/partQ[512][128], coalesced writes, no atomics.

__global__ __launch_bounds__(256) void k_bnreduce(const float* __restrict__ V, float* __restrict__ partS, float* __restrict__ partQ) {
  int t = threadIdx.x;
  int c = t & 127, half = t >> 7;
  int rs = blockIdx.x * 2 + half;            // 0..511
  float s = 0.f, s2 = 0.f;
  for (int r = rs; r < NN; r += 512) {
    float v = V[(size_t)r * 128 + c];
    s += v; s2 += v * v;
  }
  partS[rs * 128 + c] = s;
  partQ[rs * 128 + c] = s2;
}

// Stage 2: single block reduces 512 partials per channel, computes scale/shift.
__global__ __launch_bounds__(256) void k_bnfin(const float* __restrict__ partS, const float* __restrict__ partQ,
                                               const float* __restrict__ gam, const float* __restrict__ bet,
                                               float* __restrict__ sc) {
  int t = threadIdx.x;
  int c = t & 127;
  const float* src = (t < 128) ? partS : partQ;
  float s = 0.f;
#pragma unroll 8
  for (int i = 0; i < 512; ++i) s += src[i * 128 + c];
  __shared__ float sm[256];
  sm[t] = s;
  __syncthreads();
  if (t < 128) {
    float mean = sm[t] * (1.f / NN);
    float var = sm[128 + t] * (1.f / NN) - mean * mean;
    var = fmaxf(var, 0.f);
    float sg = gam[t] * rsqrtf(var + 1e-5f);
    sc[t] = sg;
    sc[128 + t] = bet[t] - mean * sg;
  }
}

// BN + ReLU in place on V (fp32) and emit bf16 copy for the next GEMM.
__global__ __launch_bounds__(256) void k_bnapply(float* __restrict__ V, unsigned short* __restrict__ Vb, const float* __restrict__ sc) {
  int idx = blockIdx.x * 256 + threadIdx.x;   // float4 index, total NN*32
  f4* V4 = (f4*)V;
  const f4* sc4 = (const f4*)sc;
  int c4 = idx & 31;
  f4 v = V4[idx];
  f4 s = sc4[c4], sh = sc4[32 + c4];
  v.x = fmaxf(v.x * s.x + sh.x, 0.f);
  v.y = fmaxf(v.y * s.y + sh.y, 0.f);
  v.z = fmaxf(v.z * s.z + sh.z, 0.f);
  v.w = fmaxf(v.w * s.w + sh.w, 0.f);
  V4[idx] = v;
  uint2 o;
  o.x = (unsigned)f2b(v.x) | ((unsigned)f2b(v.y) << 16);
  o.y = (unsigned)f2b(v.z) | ((unsigned)f2b(v.w) << 16);
  ((uint2*)Vb)[idx] = o;
}

// ---------------- pooling + final linear + BN ----------------

__global__ __launch_bounds__(256) void k_pool(const float* __restrict__ V, const int* __restrict__ batch, float* __restrict__ pooled) {
  int t = threadIdx.x;
  int c = t & 127, half = t >> 7;
  int r0 = blockIdx.x * 256;
  int rend = (r0 + 256 < NN) ? (r0 + 256) : NN;
  float s = 0.f; int cur = -1;
  for (int r = r0 + half; r < rend; r += 2) {
    int g = batch[r];
    if (g != cur) {
      if (cur >= 0) atomicAdd(&pooled[cur * 128 + c], s);
      cur = g; s = 0.f;
    }
    s += V[(size_t)r * 128 + c];
  }
  if (cur >= 0) atomicAdd(&pooled[cur * 128 + c], s);
}

// counts via binary search on sorted batch — no atomics
__global__ __launch_bounds__(128) void k_cnt(const int* __restrict__ batch, int* __restrict__ gcnt) {
  int g = threadIdx.x;
  int lo = 0, hi = NN;
  while (lo < hi) { int mid = (lo + hi) >> 1; if (batch[mid] < g) lo = mid + 1; else hi = mid; }
  int a = lo;
  lo = 0; hi = NN;
  while (lo < hi) { int mid = (lo + hi) >> 1; if (batch[mid] < g + 1) lo = mid + 1; else hi = mid; }
  gcnt[g] = lo - a;
}

__global__ __launch_bounds__(256) void k_final(const float* __restrict__ pooled, const int* __restrict__ gcnt,
                                               const float* __restrict__ Wl, const float* __restrict__ bl,
                                               const float* __restrict__ g4, const float* __restrict__ b4,
                                               float* __restrict__ out) {
  int t = threadIdx.x;
  int g = t >> 1, cls = t & 1;
  float cnt = fmaxf((float)gcnt[g], 1.f);
  float inv = 1.f / cnt;
  float z = bl[cls];
  for (int f = 0; f < 128; ++f) {
    float ps = pooled[g * 128 + f];
    z += ps * inv * Wl[f * 2 + cls] + ps * Wl[(128 + f) * 2 + cls];
  }
  __shared__ float zs[256];
  __shared__ float st[4];
  zs[t] = z;
  __syncthreads();
  if (t < 2) {
    float s = 0.f, s2 = 0.f;
    for (int gg = 0; gg < 128; ++gg) { float v = zs[gg * 2 + t]; s += v; s2 += v * v; }
    float mean = s * (1.f / 128.f);
    float var = s2 * (1.f / 128.f) - mean * mean;
    var = fmaxf(var, 0.f);
    float sc = g4[t] * rsqrtf(var + 1e-5f);
    st[t] = sc; st[2 + t] = b4[t] - mean * sc;
  }
  __syncthreads();
  out[t] = zs[t] * st[cls] + st[2 + cls];
}

// ---------------- host launcher ----------------

extern "C" void kernel_launch(void* const* d_in, const int* in_sizes, int n_in,
                              void* d_out, int out_size, void* d_ws, size_t ws_size,
                              hipStream_t stream) {
  const float* x     = (const float*)d_in[0];
  const int*   ei    = (const int*)d_in[1];
  const int*   batch = (const int*)d_in[2];
  const float* W[3]    = {(const float*)d_in[3],  (const float*)d_in[9],  (const float*)d_in[15]};
  const float* asrc[3] = {(const float*)d_in[5],  (const float*)d_in[11], (const float*)d_in[17]};
  const float* adst[3] = {(const float*)d_in[6],  (const float*)d_in[12], (const float*)d_in[18]};
  const float* gam[3]  = {(const float*)d_in[7],  (const float*)d_in[13], (const float*)d_in[19]};
  const float* bet[3]  = {(const float*)d_in[8],  (const float*)d_in[14], (const float*)d_in[20]};
  const float* Wl    = (const float*)d_in[21];
  const float* bl    = (const float*)d_in[22];
  const float* g4    = (const float*)d_in[23];
  const float* beta4 = (const float*)d_in[24];

  char* ws = (char*)d_ws;
  size_t off = 0;
  auto alloc = [&](size_t bytes) -> void* {
    void* p = (void*)(ws + off);
    off += (bytes + 255) & ~(size_t)255;
    return p;
  };

  int* counts   = (int*)alloc((size_t)NN * 4);
  int* row_off  = (int*)alloc((size_t)(NN + 1) * 4);
  int* cursor   = (int*)alloc((size_t)NN * 4);
  int* col      = (int*)alloc((size_t)NEP * 4);
  int* blk_tot  = (int*)alloc(256 * 4);
  int* blk_off  = (int*)alloc(256 * 4);
  unsigned short* Xb = (unsigned short*)alloc((size_t)NN * 128 * 2);
  unsigned short* Hb = (unsigned short*)alloc((size_t)NN * 128 * 2);
  float* V      = (float*)alloc((size_t)NN * 128 * 4);
  unsigned short* Asb = (unsigned short*)alloc((size_t)NN * 16 * 2);
  float* Ad     = (float*)alloc((size_t)NN * 16 * 4);
  unsigned short* Wt0 = (unsigned short*)alloc(16384 * 2);
  unsigned short* Wt1 = (unsigned short*)alloc(16384 * 2);
  unsigned short* Wt2 = (unsigned short*)alloc(16384 * 2);
  const unsigned short* Wt[3] = {Wt0, Wt1, Wt2};
  float* partS  = (float*)alloc(512 * 128 * 4);
  float* partQ  = (float*)alloc(512 * 128 * 4);
  float* bn_sc  = (float*)alloc(256 * 4);
  float* pooled = (float*)alloc((size_t)(NGRAPH * 128 + NGRAPH) * 4);
  int* gcnt     = (int*)(pooled + NGRAPH * 128);

  // CSR build (identical for all 3 layers)
  hipMemsetAsync(counts, 0, (size_t)NN * 4, stream);
  k_hist<<<(NEP + 255) / 256, 256, 0, stream>>>(ei, counts);
  k_scan1<<<(NN + 255) / 256, 256, 0, stream>>>(counts, row_off, blk_tot);
  k_scan2<<<1, 256, 0, stream>>>(blk_tot, blk_off, row_off, (NN + 255) / 256);
  k_scan3<<<(NN + 255) / 256, 256, 0, stream>>>(row_off, blk_off);
  hipMemcpyAsync(cursor, row_off, (size_t)NN * 4, hipMemcpyDeviceToDevice, stream);
  k_scatter<<<(NEP + 255) / 256, 256, 0, stream>>>(ei, cursor, col);

  // weights -> bf16 transposed; x -> bf16
  k_wt<<<192, 256, 0, stream>>>(W[0], W[1], W[2], Wt0, Wt1, Wt2);
  k_cast<<<(NN * 16 + 255) / 256, 256, 0, stream>>>(x, Xb, NN * 16);

  hipMemsetAsync(pooled, 0, (size_t)(NGRAPH * 128 + NGRAPH) * 4, stream);

  for (int L = 0; L < 3; ++L) {
    k_gemm<<<(NN + 127) / 128, 256, 0, stream>>>(Xb, Wt[L], Hb);
    k_coef<<<(NN * 16) / 256, 256, 0, stream>>>(Hb, asrc[L], adst[L], Asb, Ad);
    k_agg<<<NN / 8, 256, 0, stream>>>(Hb, Asb, Ad, row_off, col, V);
    k_bnreduce<<<256, 256, 0, stream>>>(V, partS, partQ);
    k_bnfin<<<1, 256, 0, stream>>>(partS, partQ, gam[L], bet[L], bn_sc);
    k_bnapply<<<(NN * 32) / 256, 256, 0, stream>>>(V, Xb, bn_sc);   // Xb becomes next layer's bf16 input
  }

  k_pool<<<(NN + 255) / 256, 256, 0, stream>>>(V, batch, pooled);
  k_cnt<<<1, 128, 0, stream>>>(batch, gcnt);
  k_final<<<1, 256, 0, stream>>>(pooled, gcnt, Wl, bl, g4, beta4, (float*)d_out);
}

// Round 5
// 409.205 us; speedup vs baseline: 1.2529x; 1.2529x over previous
//
#include <hip/hip_runtime.h>

#define NN 50000
#define NHEADS 16
#define NGRAPH 128
#define NEDGE 800000
#define NEP (NEDGE + NN)

typedef float4 f4;
typedef __attribute__((ext_vector_type(4))) float f32x4;
typedef __attribute__((ext_vector_type(8))) short s8;   // 8 bf16 (4 VGPRs)

__device__ inline unsigned short f2b(float f) {
  union { float f; unsigned u; } v; v.f = f;
  unsigned r = v.u + 0x7FFFu + ((v.u >> 16) & 1u);   // RNE
  return (unsigned short)(r >> 16);
}
__device__ inline float b2f(unsigned u16) {          // low 16 bits = bf16
  union { unsigned u; float f; } v; v.u = u16 << 16;
  return v.f;
}

// ---------------- CSR build ----------------

__global__ __launch_bounds__(256) void k_hist(const int* __restrict__ ei, int* __restrict__ counts) {
  int i = blockIdx.x * 256 + threadIdx.x;
  if (i >= NEP) return;
  int d = (i < NEDGE) ? ei[NEDGE + i] : (i - NEDGE);
  atomicAdd(&counts[d], 1);
}

__global__ __launch_bounds__(256) void k_scan1(const int* __restrict__ counts, int* __restrict__ row_off, int* __restrict__ blk_tot) {
  __shared__ int buf[256];
  int t = threadIdx.x;
  int i = blockIdx.x * 256 + t;
  int v = (i < NN) ? counts[i] : 0;
  buf[t] = v;
  __syncthreads();
  for (int off = 1; off < 256; off <<= 1) {
    int y = (t >= off) ? buf[t - off] : 0;
    __syncthreads();
    buf[t] += y;
    __syncthreads();
  }
  if (i < NN) row_off[i] = buf[t] - v;
  if (t == 255) blk_tot[blockIdx.x] = buf[255];
}

__global__ __launch_bounds__(256) void k_scan2(const int* __restrict__ blk_tot, int* __restrict__ blk_off, int* __restrict__ row_off, int nb) {
  __shared__ int buf[256];
  int t = threadIdx.x;
  int v = (t < nb) ? blk_tot[t] : 0;
  buf[t] = v;
  __syncthreads();
  for (int off = 1; off < 256; off <<= 1) {
    int y = (t >= off) ? buf[t - off] : 0;
    __syncthreads();
    buf[t] += y;
    __syncthreads();
  }
  if (t < nb) blk_off[t] = buf[t] - v;
  if (t == 255) row_off[NN] = buf[255];
}

__global__ __launch_bounds__(256) void k_scan3(int* __restrict__ row_off, const int* __restrict__ blk_off) {
  int i = blockIdx.x * 256 + threadIdx.x;
  if (i < NN) row_off[i] += blk_off[blockIdx.x];
}

__global__ __launch_bounds__(256) void k_scatter(const int* __restrict__ ei, int* __restrict__ cursor, int* __restrict__ col) {
  int i = blockIdx.x * 256 + threadIdx.x;
  if (i >= NEP) return;
  int s, d;
  if (i < NEDGE) { s = ei[i]; d = ei[NEDGE + i]; }
  else { s = d = i - NEDGE; }
  int pos = atomicAdd(&cursor[d], 1);
  col[pos] = s;
}

// ---------------- fp32 -> bf16 cast (x -> Xb) ----------------

__global__ __launch_bounds__(256) void k_cast(const float* __restrict__ X, unsigned short* __restrict__ Xb, int total8) {
  int i = blockIdx.x * 256 + threadIdx.x;      // 8 elems per thread
  if (i >= total8) return;
  const f4* X4 = (const f4*)X;
  f4 a = X4[2 * i], b = X4[2 * i + 1];
  uint4 o;
  o.x = (unsigned)f2b(a.x) | ((unsigned)f2b(a.y) << 16);
  o.y = (unsigned)f2b(a.z) | ((unsigned)f2b(a.w) << 16);
  o.z = (unsigned)f2b(b.x) | ((unsigned)f2b(b.y) << 16);
  o.w = (unsigned)f2b(b.z) | ((unsigned)f2b(b.w) << 16);
  ((uint4*)Xb)[i] = o;
}

// ---------------- W -> W^T bf16 for all 3 layers ----------------

__global__ __launch_bounds__(256) void k_wt(const float* __restrict__ W0, const float* __restrict__ W1, const float* __restrict__ W2,
                                            unsigned short* __restrict__ T0, unsigned short* __restrict__ T1, unsigned short* __restrict__ T2) {
  int idx = blockIdx.x * 256 + threadIdx.x;    // 3 * 16384
  int L = idx >> 14, r = idx & 16383;
  int n = r >> 7, k = r & 127;
  const float* W = (L == 0) ? W0 : (L == 1) ? W1 : W2;
  unsigned short* T = (L == 0) ? T0 : (L == 1) ? T1 : T2;
  T[n * 128 + k] = f2b(W[k * 128 + n]);
}

// ---------------- GEMM: Hb = bf16( Xb @ W )  via MFMA, no LDS ----------------

__global__ __launch_bounds__(256) void k_gemm(const unsigned short* __restrict__ Xb, const unsigned short* __restrict__ Wt,
                                              unsigned short* __restrict__ Hb) {
  int w = threadIdx.x >> 6, l = threadIdx.x & 63;
  int r0 = blockIdx.x * 128 + w * 32;          // this wave: rows r0..r0+31, all 128 cols
  int lr = l & 15, lg = l >> 4;
  f32x4 acc[2][8];
#pragma unroll
  for (int m = 0; m < 2; ++m)
#pragma unroll
    for (int n = 0; n < 8; ++n) acc[m][n] = (f32x4){0.f, 0.f, 0.f, 0.f};

#pragma unroll
  for (int ks = 0; ks < 4; ++ks) {
    int koff = ks * 32 + lg * 8;
    s8 a[2];
#pragma unroll
    for (int m = 0; m < 2; ++m) {
      int row = r0 + m * 16 + lr;
      row = (row < NN) ? row : (NN - 1);
      a[m] = *(const s8*)(Xb + (size_t)row * 128 + koff);
    }
    s8 b[8];
#pragma unroll
    for (int n = 0; n < 8; ++n)
      b[n] = *(const s8*)(Wt + (size_t)(n * 16 + lr) * 128 + koff);
#pragma unroll
    for (int m = 0; m < 2; ++m)
#pragma unroll
      for (int n = 0; n < 8; ++n)
        acc[m][n] = __builtin_amdgcn_mfma_f32_16x16x32_bf16(a[m], b[n], acc[m][n], 0, 0, 0);
  }

  // C/D layout: col = lane&15, row = (lane>>4)*4 + reg   [verified m89/m91]
#pragma unroll
  for (int m = 0; m < 2; ++m) {
    int rowb = r0 + m * 16 + lg * 4;
#pragma unroll
    for (int n = 0; n < 8; ++n) {
      int colb = n * 16 + lr;
#pragma unroll
      for (int reg = 0; reg < 4; ++reg) {
        int row = rowb + reg;
        if (row < NN) Hb[(size_t)row * 128 + colb] = f2b(acc[m][n][reg]);
      }
    }
  }
}

// ---------------- attention coefficients from bf16 H ----------------

__global__ __launch_bounds__(256) void k_coef(const unsigned short* __restrict__ Hb, const float* __restrict__ asrc,
                                              const float* __restrict__ adst, unsigned short* __restrict__ Asb, float* __restrict__ Ad) {
  int idx = blockIdx.x * 256 + threadIdx.x;
  if (idx >= NN * NHEADS) return;
  int n = idx >> 4, hd = idx & 15;
  uint4 hv = *(const uint4*)(Hb + (size_t)n * 128 + hd * 8);
  float h0 = b2f(hv.x & 0xffff), h1 = b2f(hv.x >> 16);
  float h2 = b2f(hv.y & 0xffff), h3 = b2f(hv.y >> 16);
  float h4 = b2f(hv.z & 0xffff), h5 = b2f(hv.z >> 16);
  float h6 = b2f(hv.w & 0xffff), h7 = b2f(hv.w >> 16);
  const f4* s4 = (const f4*)(asrc + hd * 8);
  const f4* d4 = (const f4*)(adst + hd * 8);
  f4 sa = s4[0], sb = s4[1], da = d4[0], db = d4[1];
  float as_v = h0 * sa.x + h1 * sa.y + h2 * sa.z + h3 * sa.w + h4 * sb.x + h5 * sb.y + h6 * sb.z + h7 * sb.w;
  float ad_v = h0 * da.x + h1 * da.y + h2 * da.z + h3 * da.w + h4 * db.x + h5 * db.y + h6 * db.z + h7 * db.w;
  Asb[idx] = f2b(as_v);
  Ad[idx] = ad_v;
}

// ---------------- aggregation: head-lane layout, uint4 gathers, bf16 out ----------------
// 32 lanes per node: lane = (head h = l&15) x (edge parity = l>>4).
// Each lane owns head h's 8 channels for its parity's edges; cross-parity shfl reduce at end.
// exp without max-shift: softmax shift-invariant, |e| bounded (~3) so no overflow.
// GAT bias dropped: following BN's mean subtraction absorbs per-channel constants exactly.

__global__ __launch_bounds__(256) void k_agg(const unsigned short* __restrict__ Hb, const unsigned short* __restrict__ Asb,
                                             const float* __restrict__ Ad,
                                             const int* __restrict__ row_off, const int* __restrict__ col,
                                             unsigned short* __restrict__ Vb) {
  int node = blockIdx.x * 8 + (threadIdx.x >> 5);   // 6250*8 == 50000 exactly
  int l = threadIdx.x & 31;
  int h = l & 15, par = l >> 4;
  int e0 = row_off[node], e1 = row_off[node + 1];
  float adh = Ad[node * 16 + h];
  float den = 0.f;
  float acc[8] = {0.f, 0.f, 0.f, 0.f, 0.f, 0.f, 0.f, 0.f};
  int j = e0 + par;
  for (; j + 6 < e1; j += 8) {   // 4 edges per lane in flight (8 per node)
    int s0 = col[j], s1 = col[j + 2], s2 = col[j + 4], s3 = col[j + 6];
    float a0 = b2f(Asb[s0 * 16 + h]), a1 = b2f(Asb[s1 * 16 + h]);
    float a2 = b2f(Asb[s2 * 16 + h]), a3 = b2f(Asb[s3 * 16 + h]);
    uint4 p0 = *(const uint4*)(Hb + (size_t)s0 * 128 + h * 8);
    uint4 p1 = *(const uint4*)(Hb + (size_t)s1 * 128 + h * 8);
    uint4 p2 = *(const uint4*)(Hb + (size_t)s2 * 128 + h * 8);
    uint4 p3 = *(const uint4*)(Hb + (size_t)s3 * 128 + h * 8);
    a0 += adh; a1 += adh; a2 += adh; a3 += adh;
    a0 = (a0 > 0.f) ? a0 : 0.2f * a0;  a1 = (a1 > 0.f) ? a1 : 0.2f * a1;
    a2 = (a2 > 0.f) ? a2 : 0.2f * a2;  a3 = (a3 > 0.f) ? a3 : 0.2f * a3;
    float x0 = __expf(a0), x1 = __expf(a1), x2 = __expf(a2), x3 = __expf(a3);
    den += (x0 + x1) + (x2 + x3);
    acc[0] += x0 * b2f(p0.x & 0xffff) + x1 * b2f(p1.x & 0xffff) + x2 * b2f(p2.x & 0xffff) + x3 * b2f(p3.x & 0xffff);
    acc[1] += x0 * b2f(p0.x >> 16)    + x1 * b2f(p1.x >> 16)    + x2 * b2f(p2.x >> 16)    + x3 * b2f(p3.x >> 16);
    acc[2] += x0 * b2f(p0.y & 0xffff) + x1 * b2f(p1.y & 0xffff) + x2 * b2f(p2.y & 0xffff) + x3 * b2f(p3.y & 0xffff);
    acc[3] += x0 * b2f(p0.y >> 16)    + x1 * b2f(p1.y >> 16)    + x2 * b2f(p2.y >> 16)    + x3 * b2f(p3.y >> 16);
    acc[4] += x0 * b2f(p0.z & 0xffff) + x1 * b2f(p1.z & 0xffff) + x2 * b2f(p2.z & 0xffff) + x3 * b2f(p3.z & 0xffff);
    acc[5] += x0 * b2f(p0.z >> 16)    + x1 * b2f(p1.z >> 16)    + x2 * b2f(p2.z >> 16)    + x3 * b2f(p3.z >> 16);
    acc[6] += x0 * b2f(p0.w & 0xffff) + x1 * b2f(p1.w & 0xffff) + x2 * b2f(p2.w & 0xffff) + x3 * b2f(p3.w & 0xffff);
    acc[7] += x0 * b2f(p0.w >> 16)    + x1 * b2f(p1.w >> 16)    + x2 * b2f(p2.w >> 16)    + x3 * b2f(p3.w >> 16);
  }
  for (; j < e1; j += 2) {
    int s0 = col[j];
    float a0 = b2f(Asb[s0 * 16 + h]) + adh;
    uint4 p0 = *(const uint4*)(Hb + (size_t)s0 * 128 + h * 8);
    a0 = (a0 > 0.f) ? a0 : 0.2f * a0;
    float x0 = __expf(a0);
    den += x0;
    acc[0] += x0 * b2f(p0.x & 0xffff);
    acc[1] += x0 * b2f(p0.x >> 16);
    acc[2] += x0 * b2f(p0.y & 0xffff);
    acc[3] += x0 * b2f(p0.y >> 16);
    acc[4] += x0 * b2f(p0.z & 0xffff);
    acc[5] += x0 * b2f(p0.z >> 16);
    acc[6] += x0 * b2f(p0.w & 0xffff);
    acc[7] += x0 * b2f(p0.w >> 16);
  }
  // cross-parity reduce (lane ^ 16 within the node's 32-lane group)
  den += __shfl_xor(den, 16);
#pragma unroll
  for (int k = 0; k < 8; ++k) acc[k] += __shfl_xor(acc[k], 16);
  if (par == 0) {
    float inv = 1.f / (den + 1e-16f);
    uint4 o;
    o.x = (unsigned)f2b(acc[0] * inv) | ((unsigned)f2b(acc[1] * inv) << 16);
    o.y = (unsigned)f2b(acc[2] * inv) | ((unsigned)f2b(acc[3] * inv) << 16);
    o.z = (unsigned)f2b(acc[4] * inv) | ((unsigned)f2b(acc[5] * inv) << 16);
    o.w = (unsigned)f2b(acc[6] * inv) | ((unsigned)f2b(acc[7] * inv) << 16);
    *(uint4*)(Vb + (size_t)node * 128 + h * 8) = o;
  }
}

// ---------------- BatchNorm: atomic-free two-stage reduce over bf16 V ----------------
// Stage 1: 128 blocks, LDS-combined -> one 128-ch partial (S and Q) per block.

#define BN_CHUNK 391   // 128 * 391 = 50048 >= NN

__global__ __launch_bounds__(256) void k_bnreduce(const unsigned short* __restrict__ Vb, float* __restrict__ partS, float* __restrict__ partQ) {
  int t = threadIdx.x;
  int c4 = t & 31, rs = t >> 5;               // 32 channel-quads x 8 row-streams
  int r0 = blockIdx.x * BN_CHUNK + rs;
  int rend = blockIdx.x * BN_CHUNK + BN_CHUNK;
  if (rend > NN) rend = NN;
  float s0 = 0.f, s1 = 0.f, s2 = 0.f, s3 = 0.f;
  float q0 = 0.f, q1 = 0.f, q2 = 0.f, q3 = 0.f;
  for (int r = r0; r < rend; r += 8) {
    uint2 p = *(const uint2*)(Vb + (size_t)r * 128 + c4 * 4);
    float v0 = b2f(p.x & 0xffff), v1 = b2f(p.x >> 16);
    float v2 = b2f(p.y & 0xffff), v3 = b2f(p.y >> 16);
    s0 += v0; s1 += v1; s2 += v2; s3 += v3;
    q0 += v0 * v0; q1 += v1 * v1; q2 += v2 * v2; q3 += v3 * v3;
  }
  __shared__ float sm[8][32][8];
  sm[rs][c4][0] = s0; sm[rs][c4][1] = s1; sm[rs][c4][2] = s2; sm[rs][c4][3] = s3;
  sm[rs][c4][4] = q0; sm[rs][c4][5] = q1; sm[rs][c4][6] = q2; sm[rs][c4][7] = q3;
  __syncthreads();
  if (t < 32) {
#pragma unroll
    for (int k = 0; k < 4; ++k) {
      float S = 0.f, Q = 0.f;
#pragma unroll
      for (int r = 0; r < 8; ++r) { S += sm[r][t][k]; Q += sm[r][t][4 + k]; }
      partS[blockIdx.x * 128 + t * 4 + k] = S;
      partQ[blockIdx.x * 128 + t * 4 + k] = Q;
    }
  }
}

// Stage 2: one 512-thread block (4 waves of TLP), 64 loads per thread.
__global__ __launch_bounds__(512) void k_bnfin(const float* __restrict__ partS, const float* __restrict__ partQ,
                                               const float* __restrict__ gam, const float* __restrict__ bet,
                                               float* __restrict__ sc) {
  int t = threadIdx.x;
  int c = t & 127, q = (t >> 7) & 1, hf = t >> 8;
  const float* src = q ? partQ : partS;
  float s = 0.f;
#pragma unroll 8
  for (int i = hf * 64; i < hf * 64 + 64; ++i) s += src[i * 128 + c];
  __shared__ float sm[512];
  sm[t] = s;
  __syncthreads();
  if (t < 128) {
    float S = sm[t] + sm[t + 256];
    float Q = sm[t + 128] + sm[t + 384];
    float mean = S * (1.f / NN);
    float var = fmaxf(Q * (1.f / NN) - mean * mean, 0.f);
    float sg = gam[t] * rsqrtf(var + 1e-5f);
    sc[t] = sg;
    sc[128 + t] = bet[t] - mean * sg;
  }
}

// BN + ReLU: read bf16 Vb, write bf16 Xb (next layer's GEMM input / pool input).
__global__ __launch_bounds__(256) void k_bnapply(const unsigned short* __restrict__ Vb, unsigned short* __restrict__ Xb,
                                                 const float* __restrict__ sc) {
  int idx = blockIdx.x * 256 + threadIdx.x;   // quad index, total NN*32
  int c4 = idx & 31;
  uint2 p = ((const uint2*)Vb)[idx];
  f4 s = ((const f4*)sc)[c4], sh = ((const f4*)sc)[32 + c4];
  float v0 = fmaxf(b2f(p.x & 0xffff) * s.x + sh.x, 0.f);
  float v1 = fmaxf(b2f(p.x >> 16)    * s.y + sh.y, 0.f);
  float v2 = fmaxf(b2f(p.y & 0xffff) * s.z + sh.z, 0.f);
  float v3 = fmaxf(b2f(p.y >> 16)    * s.w + sh.w, 0.f);
  uint2 o;
  o.x = (unsigned)f2b(v0) | ((unsigned)f2b(v1) << 16);
  o.y = (unsigned)f2b(v2) | ((unsigned)f2b(v3) << 16);
  ((uint2*)Xb)[idx] = o;
}

// ---------------- pooling + final linear + BN ----------------

__global__ __launch_bounds__(256) void k_pool(const unsigned short* __restrict__ Vb, const int* __restrict__ batch, float* __restrict__ pooled) {
  int t = threadIdx.x;
  int c = t & 127, half = t >> 7;
  int r0 = blockIdx.x * 256;
  int rend = (r0 + 256 < NN) ? (r0 + 256) : NN;
  float s = 0.f; int cur = -1;
  for (int r = r0 + half; r < rend; r += 2) {
    int g = batch[r];
    if (g != cur) {
      if (cur >= 0) atomicAdd(&pooled[cur * 128 + c], s);
      cur = g; s = 0.f;
    }
    s += b2f(Vb[(size_t)r * 128 + c]);
  }
  if (cur >= 0) atomicAdd(&pooled[cur * 128 + c], s);
}

// counts via binary search on sorted batch — no atomics
__global__ __launch_bounds__(128) void k_cnt(const int* __restrict__ batch, int* __restrict__ gcnt) {
  int g = threadIdx.x;
  int lo = 0, hi = NN;
  while (lo < hi) { int mid = (lo + hi) >> 1; if (batch[mid] < g) lo = mid + 1; else hi = mid; }
  int a = lo;
  lo = 0; hi = NN;
  while (lo < hi) { int mid = (lo + hi) >> 1; if (batch[mid] < g + 1) lo = mid + 1; else hi = mid; }
  gcnt[g] = lo - a;
}

__global__ __launch_bounds__(256) void k_final(const float* __restrict__ pooled, const int* __restrict__ gcnt,
                                               const float* __restrict__ Wl, const float* __restrict__ bl,
                                               const float* __restrict__ g4, const float* __restrict__ b4,
                                               float* __restrict__ out) {
  int t = threadIdx.x;
  int g = t >> 1, cls = t & 1;
  float cnt = fmaxf((float)gcnt[g], 1.f);
  float inv = 1.f / cnt;
  float z = bl[cls];
  for (int f = 0; f < 128; ++f) {
    float ps = pooled[g * 128 + f];
    z += ps * inv * Wl[f * 2 + cls] + ps * Wl[(128 + f) * 2 + cls];
  }
  __shared__ float zs[256];
  __shared__ float st[4];
  zs[t] = z;
  __syncthreads();
  if (t < 2) {
    float s = 0.f, s2 = 0.f;
    for (int gg = 0; gg < 128; ++gg) { float v = zs[gg * 2 + t]; s += v; s2 += v * v; }
    float mean = s * (1.f / 128.f);
    float var = s2 * (1.f / 128.f) - mean * mean;
    var = fmaxf(var, 0.f);
    float sc = g4[t] * rsqrtf(var + 1e-5f);
    st[t] = sc; st[2 + t] = b4[t] - mean * sc;
  }
  __syncthreads();
  out[t] = zs[t] * st[cls] + st[2 + cls];
}

// ---------------- host launcher ----------------

extern "C" void kernel_launch(void* const* d_in, const int* in_sizes, int n_in,
                              void* d_out, int out_size, void* d_ws, size_t ws_size,
                              hipStream_t stream) {
  const float* x     = (const float*)d_in[0];
  const int*   ei    = (const int*)d_in[1];
  const int*   batch = (const int*)d_in[2];
  const float* W[3]    = {(const float*)d_in[3],  (const float*)d_in[9],  (const float*)d_in[15]};
  const float* asrc[3] = {(const float*)d_in[5],  (const float*)d_in[11], (const float*)d_in[17]};
  const float* adst[3] = {(const float*)d_in[6],  (const float*)d_in[12], (const float*)d_in[18]};
  const float* gam[3]  = {(const float*)d_in[7],  (const float*)d_in[13], (const float*)d_in[19]};
  const float* bet[3]  = {(const float*)d_in[8],  (const float*)d_in[14], (const float*)d_in[20]};
  const float* Wl    = (const float*)d_in[21];
  const float* bl    = (const float*)d_in[22];
  const float* g4    = (const float*)d_in[23];
  const float* beta4 = (const float*)d_in[24];

  char* ws = (char*)d_ws;
  size_t off = 0;
  auto alloc = [&](size_t bytes) -> void* {
    void* p = (void*)(ws + off);
    off += (bytes + 255) & ~(size_t)255;
    return p;
  };

  int* counts   = (int*)alloc((size_t)NN * 4);
  int* row_off  = (int*)alloc((size_t)(NN + 1) * 4);
  int* cursor   = (int*)alloc((size_t)NN * 4);
  int* col      = (int*)alloc((size_t)NEP * 4);
  int* blk_tot  = (int*)alloc(256 * 4);
  int* blk_off  = (int*)alloc(256 * 4);
  unsigned short* Xb = (unsigned short*)alloc((size_t)NN * 128 * 2);   // GEMM input (bf16)
  unsigned short* Hb = (unsigned short*)alloc((size_t)NN * 128 * 2);   // GEMM output (bf16)
  unsigned short* Vb = (unsigned short*)alloc((size_t)NN * 128 * 2);   // agg output, pre-BN (bf16)
  unsigned short* Asb = (unsigned short*)alloc((size_t)NN * 16 * 2);
  float* Ad     = (float*)alloc((size_t)NN * 16 * 4);
  unsigned short* Wt0 = (unsigned short*)alloc(16384 * 2);
  unsigned short* Wt1 = (unsigned short*)alloc(16384 * 2);
  unsigned short* Wt2 = (unsigned short*)alloc(16384 * 2);
  const unsigned short* Wt[3] = {Wt0, Wt1, Wt2};
  float* partS  = (float*)alloc(128 * 128 * 4);
  float* partQ  = (float*)alloc(128 * 128 * 4);
  float* bn_sc  = (float*)alloc(256 * 4);
  float* pooled = (float*)alloc((size_t)(NGRAPH * 128 + NGRAPH) * 4);
  int* gcnt     = (int*)(pooled + NGRAPH * 128);

  // CSR build (identical for all 3 layers)
  hipMemsetAsync(counts, 0, (size_t)NN * 4, stream);
  k_hist<<<(NEP + 255) / 256, 256, 0, stream>>>(ei, counts);
  k_scan1<<<(NN + 255) / 256, 256, 0, stream>>>(counts, row_off, blk_tot);
  k_scan2<<<1, 256, 0, stream>>>(blk_tot, blk_off, row_off, (NN + 255) / 256);
  k_scan3<<<(NN + 255) / 256, 256, 0, stream>>>(row_off, blk_off);
  hipMemcpyAsync(cursor, row_off, (size_t)NN * 4, hipMemcpyDeviceToDevice, stream);
  k_scatter<<<(NEP + 255) / 256, 256, 0, stream>>>(ei, cursor, col);

  // weights -> bf16 transposed; x -> bf16
  k_wt<<<192, 256, 0, stream>>>(W[0], W[1], W[2], Wt0, Wt1, Wt2);
  k_cast<<<(NN * 16 + 255) / 256, 256, 0, stream>>>(x, Xb, NN * 16);

  hipMemsetAsync(pooled, 0, (size_t)(NGRAPH * 128 + NGRAPH) * 4, stream);

  for (int L = 0; L < 3; ++L) {
    k_gemm<<<(NN + 127) / 128, 256, 0, stream>>>(Xb, Wt[L], Hb);
    k_coef<<<(NN * 16) / 256, 256, 0, stream>>>(Hb, asrc[L], adst[L], Asb, Ad);
    k_agg<<<NN / 8, 256, 0, stream>>>(Hb, Asb, Ad, row_off, col, Vb);
    k_bnreduce<<<128, 256, 0, stream>>>(Vb, partS, partQ);
    k_bnfin<<<1, 512, 0, stream>>>(partS, partQ, gam[L], bet[L], bn_sc);
    k_bnapply<<<(NN * 32) / 256, 256, 0, stream>>>(Vb, Xb, bn_sc);   // Xb = next layer input / pool input
  }

  k_pool<<<(NN + 255) / 256, 256, 0, stream>>>(Xb, batch, pooled);
  k_cnt<<<1, 128, 0, stream>>>(batch, gcnt);
  k_final<<<1, 256, 0, stream>>>(pooled, gcnt, Wl, bl, g4, beta4, (float*)d_out);
}

// Round 6
// 390.743 us; speedup vs baseline: 1.3121x; 1.0472x over previous
//
#include <hip/hip_runtime.h>

#define NN 50000
#define NHEADS 16
#define NGRAPH 128
#define NEDGE 800000
#define NEP (NEDGE + NN)

// bucketed CSR build
#define EPB 2048
#define NBLK 416            // ceil(NEP / EPB)
#define NBUK 391            // ceil(NN / 128), bucket = dst >> 7

typedef float4 f4;
typedef __attribute__((ext_vector_type(4))) float f32x4;
typedef __attribute__((ext_vector_type(8))) short s8;   // 8 bf16 (4 VGPRs)

__device__ inline unsigned short f2b(float f) {
  union { float f; unsigned u; } v; v.f = f;
  unsigned r = v.u + 0x7FFFu + ((v.u >> 16) & 1u);   // RNE
  return (unsigned short)(r >> 16);
}
__device__ inline float b2f(unsigned u16) {          // low 16 bits = bf16
  union { unsigned u; float f; } v; v.u = u16 << 16;
  return v.f;
}

// ---------------- per-node counts -> row_off (unchanged) ----------------

__global__ __launch_bounds__(256) void k_hist(const int* __restrict__ ei, int* __restrict__ counts) {
  int i = blockIdx.x * 256 + threadIdx.x;
  if (i >= NEP) return;
  int d = (i < NEDGE) ? ei[NEDGE + i] : (i - NEDGE);
  atomicAdd(&counts[d], 1);
}

__global__ __launch_bounds__(256) void k_scan1(const int* __restrict__ counts, int* __restrict__ row_off, int* __restrict__ blk_tot) {
  __shared__ int buf[256];
  int t = threadIdx.x;
  int i = blockIdx.x * 256 + t;
  int v = (i < NN) ? counts[i] : 0;
  buf[t] = v;
  __syncthreads();
  for (int off = 1; off < 256; off <<= 1) {
    int y = (t >= off) ? buf[t - off] : 0;
    __syncthreads();
    buf[t] += y;
    __syncthreads();
  }
  if (i < NN) row_off[i] = buf[t] - v;
  if (t == 255) blk_tot[blockIdx.x] = buf[255];
}

__global__ __launch_bounds__(256) void k_scan2(const int* __restrict__ blk_tot, int* __restrict__ blk_off, int* __restrict__ row_off, int nb) {
  __shared__ int buf[256];
  int t = threadIdx.x;
  int v = (t < nb) ? blk_tot[t] : 0;
  buf[t] = v;
  __syncthreads();
  for (int off = 1; off < 256; off <<= 1) {
    int y = (t >= off) ? buf[t - off] : 0;
    __syncthreads();
    buf[t] += y;
    __syncthreads();
  }
  if (t < nb) blk_off[t] = buf[t] - v;
  if (t == 255) row_off[NN] = buf[255];
}

__global__ __launch_bounds__(256) void k_scan3(int* __restrict__ row_off, const int* __restrict__ blk_off) {
  int i = blockIdx.x * 256 + threadIdx.x;
  if (i < NN) row_off[i] += blk_off[blockIdx.x];
}

// ---------------- bucketed scatter: (1) per-block bucket histogram ----------------

__global__ __launch_bounds__(256) void k_bhist(const int* __restrict__ ei, int* __restrict__ cntmat) {
  __shared__ int hist[NBUK];
  int t = threadIdx.x, b = blockIdx.x;
  for (int k = t; k < NBUK; k += 256) hist[k] = 0;
  __syncthreads();
  int i0 = b * EPB;
  int i1 = i0 + EPB < NEP ? i0 + EPB : NEP;
  for (int i = i0 + t; i < i1; i += 256) {
    int d = (i < NEDGE) ? ei[NEDGE + i] : (i - NEDGE);
    atomicAdd(&hist[d >> 7], 1);
  }
  __syncthreads();
  for (int k = t; k < NBUK; k += 256) cntmat[b * NBUK + k] = hist[k];
}

// (2) per-bucket exclusive scan over blocks (in place) + bucket totals
__global__ __launch_bounds__(512) void k_bscan(int* __restrict__ cntmat, int* __restrict__ btotal) {
  __shared__ int buf[512];
  int t = threadIdx.x, k = blockIdx.x;
  int v = (t < NBLK) ? cntmat[t * NBUK + k] : 0;
  buf[t] = v;
  __syncthreads();
  for (int off = 1; off < 512; off <<= 1) {
    int y = (t >= off) ? buf[t - off] : 0;
    __syncthreads();
    buf[t] += y;
    __syncthreads();
  }
  if (t < NBLK) cntmat[t * NBUK + k] = buf[t] - v;
  if (t == 511) btotal[k] = buf[511];
}

// (3) exclusive scan of bucket totals -> bucket bases
__global__ __launch_bounds__(512) void k_bbase(const int* __restrict__ btotal, int* __restrict__ bbase) {
  __shared__ int buf[512];
  int t = threadIdx.x;
  int v = (t < NBUK) ? btotal[t] : 0;
  buf[t] = v;
  __syncthreads();
  for (int off = 1; off < 512; off <<= 1) {
    int y = (t >= off) ? buf[t - off] : 0;
    __syncthreads();
    buf[t] += y;
    __syncthreads();
  }
  if (t < NBUK) bbase[t] = buf[t] - v;
  if (t == 511) bbase[NBUK] = buf[511];   // == NEP
}

// (4) scatter edges into bucket regions; each (block,bucket) range is contiguous & preallocated
__global__ __launch_bounds__(256) void k_bscatter(const int* __restrict__ ei, const int* __restrict__ cntmat,
                                                  const int* __restrict__ bbase, unsigned* __restrict__ pairs) {
  __shared__ int cur[NBUK];
  int t = threadIdx.x, b = blockIdx.x;
  for (int k = t; k < NBUK; k += 256) cur[k] = bbase[k] + cntmat[b * NBUK + k];
  __syncthreads();
  int i0 = b * EPB;
  int i1 = i0 + EPB < NEP ? i0 + EPB : NEP;
  for (int i = i0 + t; i < i1; i += 256) {
    int s, d;
    if (i < NEDGE) { s = ei[i]; d = ei[NEDGE + i]; }
    else { s = d = i - NEDGE; }
    int pos = atomicAdd(&cur[d >> 7], 1);
    pairs[pos] = ((unsigned)(d & 127) << 16) | (unsigned)s;   // src < 65536 fits 16 bits
  }
}

// (5) within each bucket, scatter to exact CSR slots (writes span ~8.7KB -> L2-hot)
__global__ __launch_bounds__(256) void k_bfinal(const unsigned* __restrict__ pairs, const int* __restrict__ bbase,
                                                const int* __restrict__ row_off, int* __restrict__ colp) {
  __shared__ int cur[128];
  int t = threadIdx.x, k = blockIdx.x;
  int n0 = k << 7;
  if (t < 128 && n0 + t < NN) cur[t] = row_off[n0 + t];
  __syncthreads();
  int p0 = bbase[k], p1 = bbase[k + 1];
  for (int i = p0 + t; i < p1; i += 256) {
    unsigned r = pairs[i];
    int pos = atomicAdd(&cur[r >> 16], 1);
    colp[pos] = (int)(r & 0xffffu);
  }
}

// ---------------- fp32 -> bf16 cast (x -> Xb) ----------------

__global__ __launch_bounds__(256) void k_cast(const float* __restrict__ X, unsigned short* __restrict__ Xb, int total8) {
  int i = blockIdx.x * 256 + threadIdx.x;      // 8 elems per thread
  if (i >= total8) return;
  const f4* X4 = (const f4*)X;
  f4 a = X4[2 * i], b = X4[2 * i + 1];
  uint4 o;
  o.x = (unsigned)f2b(a.x) | ((unsigned)f2b(a.y) << 16);
  o.y = (unsigned)f2b(a.z) | ((unsigned)f2b(a.w) << 16);
  o.z = (unsigned)f2b(b.x) | ((unsigned)f2b(b.y) << 16);
  o.w = (unsigned)f2b(b.z) | ((unsigned)f2b(b.w) << 16);
  ((uint4*)Xb)[i] = o;
}

// ---------------- W -> W^T bf16 for all 3 layers ----------------

__global__ __launch_bounds__(256) void k_wt(const float* __restrict__ W0, const float* __restrict__ W1, const float* __restrict__ W2,
                                            unsigned short* __restrict__ T0, unsigned short* __restrict__ T1, unsigned short* __restrict__ T2) {
  int idx = blockIdx.x * 256 + threadIdx.x;    // 3 * 16384
  int L = idx >> 14, r = idx & 16383;
  int n = r >> 7, k = r & 127;
  const float* W = (L == 0) ? W0 : (L == 1) ? W1 : W2;
  unsigned short* T = (L == 0) ? T0 : (L == 1) ? T1 : T2;
  T[n * 128 + k] = f2b(W[k * 128 + n]);
}

// ---------------- GEMM: Hb = bf16( Xb @ W )  via MFMA, no LDS ----------------

__global__ __launch_bounds__(256) void k_gemm(const unsigned short* __restrict__ Xb, const unsigned short* __restrict__ Wt,
                                              unsigned short* __restrict__ Hb) {
  int w = threadIdx.x >> 6, l = threadIdx.x & 63;
  int r0 = blockIdx.x * 128 + w * 32;          // this wave: rows r0..r0+31, all 128 cols
  int lr = l & 15, lg = l >> 4;
  f32x4 acc[2][8];
#pragma unroll
  for (int m = 0; m < 2; ++m)
#pragma unroll
    for (int n = 0; n < 8; ++n) acc[m][n] = (f32x4){0.f, 0.f, 0.f, 0.f};

#pragma unroll
  for (int ks = 0; ks < 4; ++ks) {
    int koff = ks * 32 + lg * 8;
    s8 a[2];
#pragma unroll
    for (int m = 0; m < 2; ++m) {
      int row = r0 + m * 16 + lr;
      row = (row < NN) ? row : (NN - 1);
      a[m] = *(const s8*)(Xb + (size_t)row * 128 + koff);
    }
    s8 b[8];
#pragma unroll
    for (int n = 0; n < 8; ++n)
      b[n] = *(const s8*)(Wt + (size_t)(n * 16 + lr) * 128 + koff);
#pragma unroll
    for (int m = 0; m < 2; ++m)
#pragma unroll
      for (int n = 0; n < 8; ++n)
        acc[m][n] = __builtin_amdgcn_mfma_f32_16x16x32_bf16(a[m], b[n], acc[m][n], 0, 0, 0);
  }

  // C/D layout: col = lane&15, row = (lane>>4)*4 + reg   [verified m89/m91]
#pragma unroll
  for (int m = 0; m < 2; ++m) {
    int rowb = r0 + m * 16 + lg * 4;
#pragma unroll
    for (int n = 0; n < 8; ++n) {
      int colb = n * 16 + lr;
#pragma unroll
      for (int reg = 0; reg < 4; ++reg) {
        int row = rowb + reg;
        if (row < NN) Hb[(size_t)row * 128 + colb] = f2b(acc[m][n][reg]);
      }
    }
  }
}

// ---------------- attention coefficients from bf16 H ----------------

__global__ __launch_bounds__(256) void k_coef(const unsigned short* __restrict__ Hb, const float* __restrict__ asrc,
                                              const float* __restrict__ adst, unsigned short* __restrict__ Asb, float* __restrict__ Ad) {
  int idx = blockIdx.x * 256 + threadIdx.x;
  if (idx >= NN * NHEADS) return;
  int n = idx >> 4, hd = idx & 15;
  uint4 hv = *(const uint4*)(Hb + (size_t)n * 128 + hd * 8);
  float h0 = b2f(hv.x & 0xffff), h1 = b2f(hv.x >> 16);
  float h2 = b2f(hv.y & 0xffff), h3 = b2f(hv.y >> 16);
  float h4 = b2f(hv.z & 0xffff), h5 = b2f(hv.z >> 16);
  float h6 = b2f(hv.w & 0xffff), h7 = b2f(hv.w >> 16);
  const f4* s4 = (const f4*)(asrc + hd * 8);
  const f4* d4 = (const f4*)(adst + hd * 8);
  f4 sa = s4[0], sb = s4[1], da = d4[0], db = d4[1];
  float as_v = h0 * sa.x + h1 * sa.y + h2 * sa.z + h3 * sa.w + h4 * sb.x + h5 * sb.y + h6 * sb.z + h7 * sb.w;
  float ad_v = h0 * da.x + h1 * da.y + h2 * da.z + h3 * da.w + h4 * db.x + h5 * db.y + h6 * db.z + h7 * db.w;
  Asb[idx] = f2b(as_v);
  Ad[idx] = ad_v;
}

// ---------------- aggregation: head-lane layout, uint4 gathers, bf16 out ----------------
// 32 lanes per node: lane = (head h = l&15) x (edge parity = l>>4).
// exp without max-shift: softmax shift-invariant, |e| bounded (~3) so no overflow.
// GAT bias dropped: following BN's mean subtraction absorbs per-channel constants exactly.

__global__ __launch_bounds__(256) void k_agg(const unsigned short* __restrict__ Hb, const unsigned short* __restrict__ Asb,
                                             const float* __restrict__ Ad,
                                             const int* __restrict__ row_off, const int* __restrict__ col,
                                             unsigned short* __restrict__ Vb) {
  int node = blockIdx.x * 8 + (threadIdx.x >> 5);   // 6250*8 == 50000 exactly
  int l = threadIdx.x & 31;
  int h = l & 15, par = l >> 4;
  int e0 = row_off[node], e1 = row_off[node + 1];
  float adh = Ad[node * 16 + h];
  float den = 0.f;
  float acc[8] = {0.f, 0.f, 0.f, 0.f, 0.f, 0.f, 0.f, 0.f};
  int j = e0 + par;
  for (; j + 6 < e1; j += 8) {   // 4 edges per lane in flight (8 per node)
    int s0 = col[j], s1 = col[j + 2], s2 = col[j + 4], s3 = col[j + 6];
    float a0 = b2f(Asb[s0 * 16 + h]), a1 = b2f(Asb[s1 * 16 + h]);
    float a2 = b2f(Asb[s2 * 16 + h]), a3 = b2f(Asb[s3 * 16 + h]);
    uint4 p0 = *(const uint4*)(Hb + (size_t)s0 * 128 + h * 8);
    uint4 p1 = *(const uint4*)(Hb + (size_t)s1 * 128 + h * 8);
    uint4 p2 = *(const uint4*)(Hb + (size_t)s2 * 128 + h * 8);
    uint4 p3 = *(const uint4*)(Hb + (size_t)s3 * 128 + h * 8);
    a0 += adh; a1 += adh; a2 += adh; a3 += adh;
    a0 = (a0 > 0.f) ? a0 : 0.2f * a0;  a1 = (a1 > 0.f) ? a1 : 0.2f * a1;
    a2 = (a2 > 0.f) ? a2 : 0.2f * a2;  a3 = (a3 > 0.f) ? a3 : 0.2f * a3;
    float x0 = __expf(a0), x1 = __expf(a1), x2 = __expf(a2), x3 = __expf(a3);
    den += (x0 + x1) + (x2 + x3);
    acc[0] += x0 * b2f(p0.x & 0xffff) + x1 * b2f(p1.x & 0xffff) + x2 * b2f(p2.x & 0xffff) + x3 * b2f(p3.x & 0xffff);
    acc[1] += x0 * b2f(p0.x >> 16)    + x1 * b2f(p1.x >> 16)    + x2 * b2f(p2.x >> 16)    + x3 * b2f(p3.x >> 16);
    acc[2] += x0 * b2f(p0.y & 0xffff) + x1 * b2f(p1.y & 0xffff) + x2 * b2f(p2.y & 0xffff) + x3 * b2f(p3.y & 0xffff);
    acc[3] += x0 * b2f(p0.y >> 16)    + x1 * b2f(p1.y >> 16)    + x2 * b2f(p2.y >> 16)    + x3 * b2f(p3.y >> 16);
    acc[4] += x0 * b2f(p0.z & 0xffff) + x1 * b2f(p1.z & 0xffff) + x2 * b2f(p2.z & 0xffff) + x3 * b2f(p3.z & 0xffff);
    acc[5] += x0 * b2f(p0.z >> 16)    + x1 * b2f(p1.z >> 16)    + x2 * b2f(p2.z >> 16)    + x3 * b2f(p3.z >> 16);
    acc[6] += x0 * b2f(p0.w & 0xffff) + x1 * b2f(p1.w & 0xffff) + x2 * b2f(p2.w & 0xffff) + x3 * b2f(p3.w & 0xffff);
    acc[7] += x0 * b2f(p0.w >> 16)    + x1 * b2f(p1.w >> 16)    + x2 * b2f(p2.w >> 16)    + x3 * b2f(p3.w >> 16);
  }
  for (; j < e1; j += 2) {
    int s0 = col[j];
    float a0 = b2f(Asb[s0 * 16 + h]) + adh;
    uint4 p0 = *(const uint4*)(Hb + (size_t)s0 * 128 + h * 8);
    a0 = (a0 > 0.f) ? a0 : 0.2f * a0;
    float x0 = __expf(a0);
    den += x0;
    acc[0] += x0 * b2f(p0.x & 0xffff);
    acc[1] += x0 * b2f(p0.x >> 16);
    acc[2] += x0 * b2f(p0.y & 0xffff);
    acc[3] += x0 * b2f(p0.y >> 16);
    acc[4] += x0 * b2f(p0.z & 0xffff);
    acc[5] += x0 * b2f(p0.z >> 16);
    acc[6] += x0 * b2f(p0.w & 0xffff);
    acc[7] += x0 * b2f(p0.w >> 16);
  }
  // cross-parity reduce (lane ^ 16 within the node's 32-lane group)
  den += __shfl_xor(den, 16);
#pragma unroll
  for (int k = 0; k < 8; ++k) acc[k] += __shfl_xor(acc[k], 16);
  if (par == 0) {
    float inv = 1.f / (den + 1e-16f);
    uint4 o;
    o.x = (unsigned)f2b(acc[0] * inv) | ((unsigned)f2b(acc[1] * inv) << 16);
    o.y = (unsigned)f2b(acc[2] * inv) | ((unsigned)f2b(acc[3] * inv) << 16);
    o.z = (unsigned)f2b(acc[4] * inv) | ((unsigned)f2b(acc[5] * inv) << 16);
    o.w = (unsigned)f2b(acc[6] * inv) | ((unsigned)f2b(acc[7] * inv) << 16);
    *(uint4*)(Vb + (size_t)node * 128 + h * 8) = o;
  }
}

// ---------------- BatchNorm: atomic-free two-stage reduce over bf16 V ----------------

#define BN_CHUNK 391   // 128 * 391 = 50048 >= NN

__global__ __launch_bounds__(256) void k_bnreduce(const unsigned short* __restrict__ Vb, float* __restrict__ partS, float* __restrict__ partQ) {
  int t = threadIdx.x;
  int c4 = t & 31, rs = t >> 5;               // 32 channel-quads x 8 row-streams
  int r0 = blockIdx.x * BN_CHUNK + rs;
  int rend = blockIdx.x * BN_CHUNK + BN_CHUNK;
  if (rend > NN) rend = NN;
  float s0 = 0.f, s1 = 0.f, s2 = 0.f, s3 = 0.f;
  float q0 = 0.f, q1 = 0.f, q2 = 0.f, q3 = 0.f;
  for (int r = r0; r < rend; r += 8) {
    uint2 p = *(const uint2*)(Vb + (size_t)r * 128 + c4 * 4);
    float v0 = b2f(p.x & 0xffff), v1 = b2f(p.x >> 16);
    float v2 = b2f(p.y & 0xffff), v3 = b2f(p.y >> 16);
    s0 += v0; s1 += v1; s2 += v2; s3 += v3;
    q0 += v0 * v0; q1 += v1 * v1; q2 += v2 * v2; q3 += v3 * v3;
  }
  __shared__ float sm[8][32][8];
  sm[rs][c4][0] = s0; sm[rs][c4][1] = s1; sm[rs][c4][2] = s2; sm[rs][c4][3] = s3;
  sm[rs][c4][4] = q0; sm[rs][c4][5] = q1; sm[rs][c4][6] = q2; sm[rs][c4][7] = q3;
  __syncthreads();
  if (t < 32) {
#pragma unroll
    for (int k = 0; k < 4; ++k) {
      float S = 0.f, Q = 0.f;
#pragma unroll
      for (int r = 0; r < 8; ++r) { S += sm[r][t][k]; Q += sm[r][t][4 + k]; }
      partS[blockIdx.x * 128 + t * 4 + k] = S;
      partQ[blockIdx.x * 128 + t * 4 + k] = Q;
    }
  }
}

__global__ __launch_bounds__(512) void k_bnfin(const float* __restrict__ partS, const float* __restrict__ partQ,
                                               const float* __restrict__ gam, const float* __restrict__ bet,
                                               float* __restrict__ sc) {
  int t = threadIdx.x;
  int c = t & 127, q = (t >> 7) & 1, hf = t >> 8;
  const float* src = q ? partQ : partS;
  float s = 0.f;
#pragma unroll 8
  for (int i = hf * 64; i < hf * 64 + 64; ++i) s += src[i * 128 + c];
  __shared__ float sm[512];
  sm[t] = s;
  __syncthreads();
  if (t < 128) {
    float S = sm[t] + sm[t + 256];
    float Q = sm[t + 128] + sm[t + 384];
    float mean = S * (1.f / NN);
    float var = fmaxf(Q * (1.f / NN) - mean * mean, 0.f);
    float sg = gam[t] * rsqrtf(var + 1e-5f);
    sc[t] = sg;
    sc[128 + t] = bet[t] - mean * sg;
  }
}

__global__ __launch_bounds__(256) void k_bnapply(const unsigned short* __restrict__ Vb, unsigned short* __restrict__ Xb,
                                                 const float* __restrict__ sc) {
  int idx = blockIdx.x * 256 + threadIdx.x;   // quad index, total NN*32
  int c4 = idx & 31;
  uint2 p = ((const uint2*)Vb)[idx];
  f4 s = ((const f4*)sc)[c4], sh = ((const f4*)sc)[32 + c4];
  float v0 = fmaxf(b2f(p.x & 0xffff) * s.x + sh.x, 0.f);
  float v1 = fmaxf(b2f(p.x >> 16)    * s.y + sh.y, 0.f);
  float v2 = fmaxf(b2f(p.y & 0xffff) * s.z + sh.z, 0.f);
  float v3 = fmaxf(b2f(p.y >> 16)    * s.w + sh.w, 0.f);
  uint2 o;
  o.x = (unsigned)f2b(v0) | ((unsigned)f2b(v1) << 16);
  o.y = (unsigned)f2b(v2) | ((unsigned)f2b(v3) << 16);
  ((uint2*)Xb)[idx] = o;
}

// ---------------- pooling + final linear + BN ----------------

__global__ __launch_bounds__(256) void k_pool(const unsigned short* __restrict__ Vb, const int* __restrict__ batch, float* __restrict__ pooled) {
  int t = threadIdx.x;
  int c = t & 127, half = t >> 7;
  int r0 = blockIdx.x * 256;
  int rend = (r0 + 256 < NN) ? (r0 + 256) : NN;
  float s = 0.f; int cur = -1;
  for (int r = r0 + half; r < rend; r += 2) {
    int g = batch[r];
    if (g != cur) {
      if (cur >= 0) atomicAdd(&pooled[cur * 128 + c], s);
      cur = g; s = 0.f;
    }
    s += b2f(Vb[(size_t)r * 128 + c]);
  }
  if (cur >= 0) atomicAdd(&pooled[cur * 128 + c], s);
}

__global__ __launch_bounds__(128) void k_cnt(const int* __restrict__ batch, int* __restrict__ gcnt) {
  int g = threadIdx.x;
  int lo = 0, hi = NN;
  while (lo < hi) { int mid = (lo + hi) >> 1; if (batch[mid] < g) lo = mid + 1; else hi = mid; }
  int a = lo;
  lo = 0; hi = NN;
  while (lo < hi) { int mid = (lo + hi) >> 1; if (batch[mid] < g + 1) lo = mid + 1; else hi = mid; }
  gcnt[g] = lo - a;
}

__global__ __launch_bounds__(256) void k_final(const float* __restrict__ pooled, const int* __restrict__ gcnt,
                                               const float* __restrict__ Wl, const float* __restrict__ bl,
                                               const float* __restrict__ g4, const float* __restrict__ b4,
                                               float* __restrict__ out) {
  int t = threadIdx.x;
  int g = t >> 1, cls = t & 1;
  float cnt = fmaxf((float)gcnt[g], 1.f);
  float inv = 1.f / cnt;
  float z = bl[cls];
  for (int f = 0; f < 128; ++f) {
    float ps = pooled[g * 128 + f];
    z += ps * inv * Wl[f * 2 + cls] + ps * Wl[(128 + f) * 2 + cls];
  }
  __shared__ float zs[256];
  __shared__ float st[4];
  zs[t] = z;
  __syncthreads();
  if (t < 2) {
    float s = 0.f, s2 = 0.f;
    for (int gg = 0; gg < 128; ++gg) { float v = zs[gg * 2 + t]; s += v; s2 += v * v; }
    float mean = s * (1.f / 128.f);
    float var = s2 * (1.f / 128.f) - mean * mean;
    var = fmaxf(var, 0.f);
    float sc = g4[t] * rsqrtf(var + 1e-5f);
    st[t] = sc; st[2 + t] = b4[t] - mean * sc;
  }
  __syncthreads();
  out[t] = zs[t] * st[cls] + st[2 + cls];
}

// ---------------- host launcher ----------------

extern "C" void kernel_launch(void* const* d_in, const int* in_sizes, int n_in,
                              void* d_out, int out_size, void* d_ws, size_t ws_size,
                              hipStream_t stream) {
  const float* x     = (const float*)d_in[0];
  const int*   ei    = (const int*)d_in[1];
  const int*   batch = (const int*)d_in[2];
  const float* W[3]    = {(const float*)d_in[3],  (const float*)d_in[9],  (const float*)d_in[15]};
  const float* asrc[3] = {(const float*)d_in[5],  (const float*)d_in[11], (const float*)d_in[17]};
  const float* adst[3] = {(const float*)d_in[6],  (const float*)d_in[12], (const float*)d_in[18]};
  const float* gam[3]  = {(const float*)d_in[7],  (const float*)d_in[13], (const float*)d_in[19]};
  const float* bet[3]  = {(const float*)d_in[8],  (const float*)d_in[14], (const float*)d_in[20]};
  const float* Wl    = (const float*)d_in[21];
  const float* bl    = (const float*)d_in[22];
  const float* g4    = (const float*)d_in[23];
  const float* beta4 = (const float*)d_in[24];

  char* ws = (char*)d_ws;
  size_t off = 0;
  auto alloc = [&](size_t bytes) -> void* {
    void* p = (void*)(ws + off);
    off += (bytes + 255) & ~(size_t)255;
    return p;
  };

  int* counts   = (int*)alloc((size_t)NN * 4);
  int* row_off  = (int*)alloc((size_t)(NN + 1) * 4);
  int* col      = (int*)alloc((size_t)NEP * 4);
  int* blk_tot  = (int*)alloc(256 * 4);
  int* blk_off  = (int*)alloc(256 * 4);
  int* cntmat   = (int*)alloc((size_t)NBLK * NBUK * 4);
  int* btotal   = (int*)alloc((size_t)NBUK * 4);
  int* bbase    = (int*)alloc((size_t)(NBUK + 1) * 4);
  unsigned* pairs = (unsigned*)alloc((size_t)NEP * 4);
  unsigned short* Xb = (unsigned short*)alloc((size_t)NN * 128 * 2);   // GEMM input (bf16)
  unsigned short* Hb = (unsigned short*)alloc((size_t)NN * 128 * 2);   // GEMM output (bf16)
  unsigned short* Vb = (unsigned short*)alloc((size_t)NN * 128 * 2);   // agg output, pre-BN (bf16)
  unsigned short* Asb = (unsigned short*)alloc((size_t)NN * 16 * 2);
  float* Ad     = (float*)alloc((size_t)NN * 16 * 4);
  unsigned short* Wt0 = (unsigned short*)alloc(16384 * 2);
  unsigned short* Wt1 = (unsigned short*)alloc(16384 * 2);
  unsigned short* Wt2 = (unsigned short*)alloc(16384 * 2);
  const unsigned short* Wt[3] = {Wt0, Wt1, Wt2};
  float* partS  = (float*)alloc(128 * 128 * 4);
  float* partQ  = (float*)alloc(128 * 128 * 4);
  float* bn_sc  = (float*)alloc(256 * 4);
  float* pooled = (float*)alloc((size_t)(NGRAPH * 128 + NGRAPH) * 4);
  int* gcnt     = (int*)(pooled + NGRAPH * 128);

  // ---- CSR build: row_off (per-node) + bucketed scatter ----
  hipMemsetAsync(counts, 0, (size_t)NN * 4, stream);
  k_hist<<<(NEP + 255) / 256, 256, 0, stream>>>(ei, counts);
  k_scan1<<<(NN + 255) / 256, 256, 0, stream>>>(counts, row_off, blk_tot);
  k_scan2<<<1, 256, 0, stream>>>(blk_tot, blk_off, row_off, (NN + 255) / 256);
  k_scan3<<<(NN + 255) / 256, 256, 0, stream>>>(row_off, blk_off);

  k_bhist<<<NBLK, 256, 0, stream>>>(ei, cntmat);
  k_bscan<<<NBUK, 512, 0, stream>>>(cntmat, btotal);
  k_bbase<<<1, 512, 0, stream>>>(btotal, bbase);
  k_bscatter<<<NBLK, 256, 0, stream>>>(ei, cntmat, bbase, pairs);
  k_bfinal<<<NBUK, 256, 0, stream>>>(pairs, bbase, row_off, col);

  // weights -> bf16 transposed; x -> bf16
  k_wt<<<192, 256, 0, stream>>>(W[0], W[1], W[2], Wt0, Wt1, Wt2);
  k_cast<<<(NN * 16 + 255) / 256, 256, 0, stream>>>(x, Xb, NN * 16);

  hipMemsetAsync(pooled, 0, (size_t)(NGRAPH * 128 + NGRAPH) * 4, stream);

  for (int L = 0; L < 3; ++L) {
    k_gemm<<<(NN + 127) / 128, 256, 0, stream>>>(Xb, Wt[L], Hb);
    k_coef<<<(NN * 16) / 256, 256, 0, stream>>>(Hb, asrc[L], adst[L], Asb, Ad);
    k_agg<<<NN / 8, 256, 0, stream>>>(Hb, Asb, Ad, row_off, col, Vb);
    k_bnreduce<<<128, 256, 0, stream>>>(Vb, partS, partQ);
    k_bnfin<<<1, 512, 0, stream>>>(partS, partQ, gam[L], bet[L], bn_sc);
    k_bnapply<<<(NN * 32) / 256, 256, 0, stream>>>(Vb, Xb, bn_sc);   // Xb = next layer input / pool input
  }

  k_pool<<<(NN + 255) / 256, 256, 0, stream>>>(Xb, batch, pooled);
  k_cnt<<<1, 128, 0, stream>>>(batch, gcnt);
  k_final<<<1, 256, 0, stream>>>(pooled, gcnt, Wl, bl, g4, beta4, (float*)d_out);
}

// Round 7
// 349.446 us; speedup vs baseline: 1.4672x; 1.1182x over previous
//
#include <hip/hip_runtime.h>

#define NN 50000
#define NHEADS 16
#define NGRAPH 128
#define NEDGE 800000
#define NEP (NEDGE + NN)

// bucketed CSR build
#define EPB 2048
#define NBLK 416            // ceil(NEP / EPB)
#define NBUK 391            // ceil(NN / 128), bucket = dst >> 7

typedef float4 f4;
typedef __attribute__((ext_vector_type(4))) float f32x4;
typedef __attribute__((ext_vector_type(8))) short s8;   // 8 bf16 (4 VGPRs)

__device__ inline unsigned short f2b(float f) {
  union { float f; unsigned u; } v; v.f = f;
  unsigned r = v.u + 0x7FFFu + ((v.u >> 16) & 1u);   // RNE
  return (unsigned short)(r >> 16);
}
__device__ inline float b2f(unsigned u16) {          // low 16 bits = bf16
  union { unsigned u; float f; } v; v.u = u16 << 16;
  return v.f;
}

// ---------------- per-node counts -> row_off ----------------

__global__ __launch_bounds__(256) void k_hist(const int* __restrict__ ei, int* __restrict__ counts) {
  int i = blockIdx.x * 256 + threadIdx.x;
  if (i >= NEP) return;
  int d = (i < NEDGE) ? ei[NEDGE + i] : (i - NEDGE);
  atomicAdd(&counts[d], 1);
}

__global__ __launch_bounds__(256) void k_scan1(const int* __restrict__ counts, int* __restrict__ row_off, int* __restrict__ blk_tot) {
  __shared__ int buf[256];
  int t = threadIdx.x;
  int i = blockIdx.x * 256 + t;
  int v = (i < NN) ? counts[i] : 0;
  buf[t] = v;
  __syncthreads();
  for (int off = 1; off < 256; off <<= 1) {
    int y = (t >= off) ? buf[t - off] : 0;
    __syncthreads();
    buf[t] += y;
    __syncthreads();
  }
  if (i < NN) row_off[i] = buf[t] - v;
  if (t == 255) blk_tot[blockIdx.x] = buf[255];
}

__global__ __launch_bounds__(256) void k_scan2(const int* __restrict__ blk_tot, int* __restrict__ blk_off, int* __restrict__ row_off, int nb) {
  __shared__ int buf[256];
  int t = threadIdx.x;
  int v = (t < nb) ? blk_tot[t] : 0;
  buf[t] = v;
  __syncthreads();
  for (int off = 1; off < 256; off <<= 1) {
    int y = (t >= off) ? buf[t - off] : 0;
    __syncthreads();
    buf[t] += y;
    __syncthreads();
  }
  if (t < nb) blk_off[t] = buf[t] - v;
  if (t == 255) row_off[NN] = buf[255];
}

__global__ __launch_bounds__(256) void k_scan3(int* __restrict__ row_off, const int* __restrict__ blk_off) {
  int i = blockIdx.x * 256 + threadIdx.x;
  if (i < NN) row_off[i] += blk_off[blockIdx.x];
}

// ---------------- bucketed scatter ----------------
// Bucket k = nodes [k*128, (k+1)*128). Region of bucket k in pairs/col is
// [row_off[k*128], row_off[min((k+1)*128, NN)]) — same segmentation, no extra scan.

__global__ __launch_bounds__(256) void k_bhist(const int* __restrict__ ei, int* __restrict__ cntmat) {
  __shared__ int hist[NBUK];
  int t = threadIdx.x, b = blockIdx.x;
  for (int k = t; k < NBUK; k += 256) hist[k] = 0;
  __syncthreads();
  int i0 = b * EPB;
  int i1 = i0 + EPB < NEP ? i0 + EPB : NEP;
  for (int i = i0 + t; i < i1; i += 256) {
    int d = (i < NEDGE) ? ei[NEDGE + i] : (i - NEDGE);
    atomicAdd(&hist[d >> 7], 1);
  }
  __syncthreads();
  for (int k = t; k < NBUK; k += 256) cntmat[b * NBUK + k] = hist[k];
}

// per-bucket exclusive scan over blocks (in place)
__global__ __launch_bounds__(512) void k_bscan(int* __restrict__ cntmat) {
  __shared__ int buf[512];
  int t = threadIdx.x, k = blockIdx.x;
  int v = (t < NBLK) ? cntmat[t * NBUK + k] : 0;
  buf[t] = v;
  __syncthreads();
  for (int off = 1; off < 512; off <<= 1) {
    int y = (t >= off) ? buf[t - off] : 0;
    __syncthreads();
    buf[t] += y;
    __syncthreads();
  }
  if (t < NBLK) cntmat[t * NBUK + k] = buf[t] - v;
}

__global__ __launch_bounds__(256) void k_bscatter(const int* __restrict__ ei, const int* __restrict__ cntmat,
                                                  const int* __restrict__ row_off, unsigned* __restrict__ pairs) {
  __shared__ int cur[NBUK];
  int t = threadIdx.x, b = blockIdx.x;
  for (int k = t; k < NBUK; k += 256) cur[k] = row_off[k << 7] + cntmat[b * NBUK + k];
  __syncthreads();
  int i0 = b * EPB;
  int i1 = i0 + EPB < NEP ? i0 + EPB : NEP;
  for (int i = i0 + t; i < i1; i += 256) {
    int s, d;
    if (i < NEDGE) { s = ei[i]; d = ei[NEDGE + i]; }
    else { s = d = i - NEDGE; }
    int pos = atomicAdd(&cur[d >> 7], 1);
    pairs[pos] = ((unsigned)(d & 127) << 16) | (unsigned)s;   // src < 65536 fits 16 bits
  }
}

// within each bucket, scatter to exact CSR slots (writes span ~8.7KB -> L2-hot)
__global__ __launch_bounds__(256) void k_bfinal(const unsigned* __restrict__ pairs,
                                                const int* __restrict__ row_off, int* __restrict__ colp) {
  __shared__ int cur[128];
  int t = threadIdx.x, k = blockIdx.x;
  int n0 = k << 7;
  if (t < 128 && n0 + t < NN) cur[t] = row_off[n0 + t];
  __syncthreads();
  int nend = (k + 1) << 7; if (nend > NN) nend = NN;
  int p0 = row_off[n0], p1 = row_off[nend];
  for (int i = p0 + t; i < p1; i += 256) {
    unsigned r = pairs[i];
    int pos = atomicAdd(&cur[r >> 16], 1);
    colp[pos] = (int)(r & 0xffffu);
  }
}

// ---------------- fp32 -> bf16 cast (x -> Xb) ----------------

__global__ __launch_bounds__(256) void k_cast(const float* __restrict__ X, unsigned short* __restrict__ Xb, int total8) {
  int i = blockIdx.x * 256 + threadIdx.x;      // 8 elems per thread
  if (i >= total8) return;
  const f4* X4 = (const f4*)X;
  f4 a = X4[2 * i], b = X4[2 * i + 1];
  uint4 o;
  o.x = (unsigned)f2b(a.x) | ((unsigned)f2b(a.y) << 16);
  o.y = (unsigned)f2b(a.z) | ((unsigned)f2b(a.w) << 16);
  o.z = (unsigned)f2b(b.x) | ((unsigned)f2b(b.y) << 16);
  o.w = (unsigned)f2b(b.z) | ((unsigned)f2b(b.w) << 16);
  ((uint4*)Xb)[i] = o;
}

// ---------------- W -> W^T bf16 for all 3 layers ----------------

__global__ __launch_bounds__(256) void k_wt(const float* __restrict__ W0, const float* __restrict__ W1, const float* __restrict__ W2,
                                            unsigned short* __restrict__ T0, unsigned short* __restrict__ T1, unsigned short* __restrict__ T2) {
  int idx = blockIdx.x * 256 + threadIdx.x;    // 3 * 16384
  int L = idx >> 14, r = idx & 16383;
  int n = r >> 7, k = r & 127;
  const float* W = (L == 0) ? W0 : (L == 1) ? W1 : W2;
  unsigned short* T = (L == 0) ? T0 : (L == 1) ? T1 : T2;
  T[n * 128 + k] = f2b(W[k * 128 + n]);
}

// ---------------- GEMM: Hb = bf16( Xb @ W )  via MFMA, no LDS ----------------

__global__ __launch_bounds__(256) void k_gemm(const unsigned short* __restrict__ Xb, const unsigned short* __restrict__ Wt,
                                              unsigned short* __restrict__ Hb) {
  int w = threadIdx.x >> 6, l = threadIdx.x & 63;
  int r0 = blockIdx.x * 128 + w * 32;          // this wave: rows r0..r0+31, all 128 cols
  int lr = l & 15, lg = l >> 4;
  f32x4 acc[2][8];
#pragma unroll
  for (int m = 0; m < 2; ++m)
#pragma unroll
    for (int n = 0; n < 8; ++n) acc[m][n] = (f32x4){0.f, 0.f, 0.f, 0.f};

#pragma unroll
  for (int ks = 0; ks < 4; ++ks) {
    int koff = ks * 32 + lg * 8;
    s8 a[2];
#pragma unroll
    for (int m = 0; m < 2; ++m) {
      int row = r0 + m * 16 + lr;
      row = (row < NN) ? row : (NN - 1);
      a[m] = *(const s8*)(Xb + (size_t)row * 128 + koff);
    }
    s8 b[8];
#pragma unroll
    for (int n = 0; n < 8; ++n)
      b[n] = *(const s8*)(Wt + (size_t)(n * 16 + lr) * 128 + koff);
#pragma unroll
    for (int m = 0; m < 2; ++m)
#pragma unroll
      for (int n = 0; n < 8; ++n)
        acc[m][n] = __builtin_amdgcn_mfma_f32_16x16x32_bf16(a[m], b[n], acc[m][n], 0, 0, 0);
  }

  // C/D layout: col = lane&15, row = (lane>>4)*4 + reg   [verified m89/m91]
#pragma unroll
  for (int m = 0; m < 2; ++m) {
    int rowb = r0 + m * 16 + lg * 4;
#pragma unroll
    for (int n = 0; n < 8; ++n) {
      int colb = n * 16 + lr;
#pragma unroll
      for (int reg = 0; reg < 4; ++reg) {
        int row = rowb + reg;
        if (row < NN) Hb[(size_t)row * 128 + colb] = f2b(acc[m][n][reg]);
      }
    }
  }
}

// ---------------- attention coefficients from bf16 H ----------------

__global__ __launch_bounds__(256) void k_coef(const unsigned short* __restrict__ Hb, const float* __restrict__ asrc,
                                              const float* __restrict__ adst, unsigned short* __restrict__ Asb, float* __restrict__ Ad) {
  int idx = blockIdx.x * 256 + threadIdx.x;
  if (idx >= NN * NHEADS) return;
  int n = idx >> 4, hd = idx & 15;
  uint4 hv = *(const uint4*)(Hb + (size_t)n * 128 + hd * 8);
  float h0 = b2f(hv.x & 0xffff), h1 = b2f(hv.x >> 16);
  float h2 = b2f(hv.y & 0xffff), h3 = b2f(hv.y >> 16);
  float h4 = b2f(hv.z & 0xffff), h5 = b2f(hv.z >> 16);
  float h6 = b2f(hv.w & 0xffff), h7 = b2f(hv.w >> 16);
  const f4* s4 = (const f4*)(asrc + hd * 8);
  const f4* d4 = (const f4*)(adst + hd * 8);
  f4 sa = s4[0], sb = s4[1], da = d4[0], db = d4[1];
  float as_v = h0 * sa.x + h1 * sa.y + h2 * sa.z + h3 * sa.w + h4 * sb.x + h5 * sb.y + h6 * sb.z + h7 * sb.w;
  float ad_v = h0 * da.x + h1 * da.y + h2 * da.z + h3 * da.w + h4 * db.x + h5 * db.y + h6 * db.z + h7 * db.w;
  Asb[idx] = f2b(as_v);
  Ad[idx] = ad_v;
}

// ---------------- aggregation: head-lane layout, uint4 gathers, bf16 out ----------------

__global__ __launch_bounds__(256) void k_agg(const unsigned short* __restrict__ Hb, const unsigned short* __restrict__ Asb,
                                             const float* __restrict__ Ad,
                                             const int* __restrict__ row_off, const int* __restrict__ col,
                                             unsigned short* __restrict__ Vb) {
  int node = blockIdx.x * 8 + (threadIdx.x >> 5);   // 6250*8 == 50000 exactly
  int l = threadIdx.x & 31;
  int h = l & 15, par = l >> 4;
  int e0 = row_off[node], e1 = row_off[node + 1];
  float adh = Ad[node * 16 + h];
  float den = 0.f;
  float acc[8] = {0.f, 0.f, 0.f, 0.f, 0.f, 0.f, 0.f, 0.f};
  int j = e0 + par;
  for (; j + 6 < e1; j += 8) {   // 4 edges per lane in flight (8 per node)
    int s0 = col[j], s1 = col[j + 2], s2 = col[j + 4], s3 = col[j + 6];
    float a0 = b2f(Asb[s0 * 16 + h]), a1 = b2f(Asb[s1 * 16 + h]);
    float a2 = b2f(Asb[s2 * 16 + h]), a3 = b2f(Asb[s3 * 16 + h]);
    uint4 p0 = *(const uint4*)(Hb + (size_t)s0 * 128 + h * 8);
    uint4 p1 = *(const uint4*)(Hb + (size_t)s1 * 128 + h * 8);
    uint4 p2 = *(const uint4*)(Hb + (size_t)s2 * 128 + h * 8);
    uint4 p3 = *(const uint4*)(Hb + (size_t)s3 * 128 + h * 8);
    a0 += adh; a1 += adh; a2 += adh; a3 += adh;
    a0 = (a0 > 0.f) ? a0 : 0.2f * a0;  a1 = (a1 > 0.f) ? a1 : 0.2f * a1;
    a2 = (a2 > 0.f) ? a2 : 0.2f * a2;  a3 = (a3 > 0.f) ? a3 : 0.2f * a3;
    float x0 = __expf(a0), x1 = __expf(a1), x2 = __expf(a2), x3 = __expf(a3);
    den += (x0 + x1) + (x2 + x3);
    acc[0] += x0 * b2f(p0.x & 0xffff) + x1 * b2f(p1.x & 0xffff) + x2 * b2f(p2.x & 0xffff) + x3 * b2f(p3.x & 0xffff);
    acc[1] += x0 * b2f(p0.x >> 16)    + x1 * b2f(p1.x >> 16)    + x2 * b2f(p2.x >> 16)    + x3 * b2f(p3.x >> 16);
    acc[2] += x0 * b2f(p0.y & 0xffff) + x1 * b2f(p1.y & 0xffff) + x2 * b2f(p2.y & 0xffff) + x3 * b2f(p3.y & 0xffff);
    acc[3] += x0 * b2f(p0.y >> 16)    + x1 * b2f(p1.y >> 16)    + x2 * b2f(p2.y >> 16)    + x3 * b2f(p3.y >> 16);
    acc[4] += x0 * b2f(p0.z & 0xffff) + x1 * b2f(p1.z & 0xffff) + x2 * b2f(p2.z & 0xffff) + x3 * b2f(p3.z & 0xffff);
    acc[5] += x0 * b2f(p0.z >> 16)    + x1 * b2f(p1.z >> 16)    + x2 * b2f(p2.z >> 16)    + x3 * b2f(p3.z >> 16);
    acc[6] += x0 * b2f(p0.w & 0xffff) + x1 * b2f(p1.w & 0xffff) + x2 * b2f(p2.w & 0xffff) + x3 * b2f(p3.w & 0xffff);
    acc[7] += x0 * b2f(p0.w >> 16)    + x1 * b2f(p1.w >> 16)    + x2 * b2f(p2.w >> 16)    + x3 * b2f(p3.w >> 16);
  }
  for (; j < e1; j += 2) {
    int s0 = col[j];
    float a0 = b2f(Asb[s0 * 16 + h]) + adh;
    uint4 p0 = *(const uint4*)(Hb + (size_t)s0 * 128 + h * 8);
    a0 = (a0 > 0.f) ? a0 : 0.2f * a0;
    float x0 = __expf(a0);
    den += x0;
    acc[0] += x0 * b2f(p0.x & 0xffff);
    acc[1] += x0 * b2f(p0.x >> 16);
    acc[2] += x0 * b2f(p0.y & 0xffff);
    acc[3] += x0 * b2f(p0.y >> 16);
    acc[4] += x0 * b2f(p0.z & 0xffff);
    acc[5] += x0 * b2f(p0.z >> 16);
    acc[6] += x0 * b2f(p0.w & 0xffff);
    acc[7] += x0 * b2f(p0.w >> 16);
  }
  den += __shfl_xor(den, 16);
#pragma unroll
  for (int k = 0; k < 8; ++k) acc[k] += __shfl_xor(acc[k], 16);
  if (par == 0) {
    float inv = 1.f / (den + 1e-16f);
    uint4 o;
    o.x = (unsigned)f2b(acc[0] * inv) | ((unsigned)f2b(acc[1] * inv) << 16);
    o.y = (unsigned)f2b(acc[2] * inv) | ((unsigned)f2b(acc[3] * inv) << 16);
    o.z = (unsigned)f2b(acc[4] * inv) | ((unsigned)f2b(acc[5] * inv) << 16);
    o.w = (unsigned)f2b(acc[6] * inv) | ((unsigned)f2b(acc[7] * inv) << 16);
    *(uint4*)(Vb + (size_t)node * 128 + h * 8) = o;
  }
}

// ---------------- BatchNorm: atomic-free two-stage reduce over bf16 V ----------------

#define BN_CHUNK 391   // 128 * 391 = 50048 >= NN

__global__ __launch_bounds__(256) void k_bnreduce(const unsigned short* __restrict__ Vb, float* __restrict__ partS, float* __restrict__ partQ) {
  int t = threadIdx.x;
  int c4 = t & 31, rs = t >> 5;               // 32 channel-quads x 8 row-streams
  int r0 = blockIdx.x * BN_CHUNK + rs;
  int rend = blockIdx.x * BN_CHUNK + BN_CHUNK;
  if (rend > NN) rend = NN;
  float s0 = 0.f, s1 = 0.f, s2 = 0.f, s3 = 0.f;
  float q0 = 0.f, q1 = 0.f, q2 = 0.f, q3 = 0.f;
  for (int r = r0; r < rend; r += 8) {
    uint2 p = *(const uint2*)(Vb + (size_t)r * 128 + c4 * 4);
    float v0 = b2f(p.x & 0xffff), v1 = b2f(p.x >> 16);
    float v2 = b2f(p.y & 0xffff), v3 = b2f(p.y >> 16);
    s0 += v0; s1 += v1; s2 += v2; s3 += v3;
    q0 += v0 * v0; q1 += v1 * v1; q2 += v2 * v2; q3 += v3 * v3;
  }
  __shared__ float sm[8][32][8];
  sm[rs][c4][0] = s0; sm[rs][c4][1] = s1; sm[rs][c4][2] = s2; sm[rs][c4][3] = s3;
  sm[rs][c4][4] = q0; sm[rs][c4][5] = q1; sm[rs][c4][6] = q2; sm[rs][c4][7] = q3;
  __syncthreads();
  if (t < 32) {
#pragma unroll
    for (int k = 0; k < 4; ++k) {
      float S = 0.f, Q = 0.f;
#pragma unroll
      for (int r = 0; r < 8; ++r) { S += sm[r][t][k]; Q += sm[r][t][4 + k]; }
      partS[blockIdx.x * 128 + t * 4 + k] = S;
      partQ[blockIdx.x * 128 + t * 4 + k] = Q;
    }
  }
}

__global__ __launch_bounds__(512) void k_bnfin(const float* __restrict__ partS, const float* __restrict__ partQ,
                                               const float* __restrict__ gam, const float* __restrict__ bet,
                                               float* __restrict__ sc) {
  int t = threadIdx.x;
  int c = t & 127, q = (t >> 7) & 1, hf = t >> 8;
  const float* src = q ? partQ : partS;
  float s = 0.f;
#pragma unroll 8
  for (int i = hf * 64; i < hf * 64 + 64; ++i) s += src[i * 128 + c];
  __shared__ float sm[512];
  sm[t] = s;
  __syncthreads();
  if (t < 128) {
    float S = sm[t] + sm[t + 256];
    float Q = sm[t + 128] + sm[t + 384];
    float mean = S * (1.f / NN);
    float var = fmaxf(Q * (1.f / NN) - mean * mean, 0.f);
    float sg = gam[t] * rsqrtf(var + 1e-5f);
    sc[t] = sg;
    sc[128 + t] = bet[t] - mean * sg;
  }
}

__global__ __launch_bounds__(256) void k_bnapply(const unsigned short* __restrict__ Vb, unsigned short* __restrict__ Xb,
                                                 const float* __restrict__ sc) {
  int idx = blockIdx.x * 256 + threadIdx.x;   // quad index, total NN*32
  int c4 = idx & 31;
  uint2 p = ((const uint2*)Vb)[idx];
  f4 s = ((const f4*)sc)[c4], sh = ((const f4*)sc)[32 + c4];
  float v0 = fmaxf(b2f(p.x & 0xffff) * s.x + sh.x, 0.f);
  float v1 = fmaxf(b2f(p.x >> 16)    * s.y + sh.y, 0.f);
  float v2 = fmaxf(b2f(p.y & 0xffff) * s.z + sh.z, 0.f);
  float v3 = fmaxf(b2f(p.y >> 16)    * s.w + sh.w, 0.f);
  uint2 o;
  o.x = (unsigned)f2b(v0) | ((unsigned)f2b(v1) << 16);
  o.y = (unsigned)f2b(v2) | ((unsigned)f2b(v3) << 16);
  ((uint2*)Xb)[idx] = o;
}

// ---------------- graph bounds (sorted batch) + pooling + final ----------------

// gstart[g] = lower_bound(batch, g), g = 0..128  (gstart[128] == NN)
__global__ __launch_bounds__(256) void k_gb(const int* __restrict__ batch, int* __restrict__ gstart) {
  int g = threadIdx.x;
  if (g > NGRAPH) return;
  int lo = 0, hi = NN;
  while (lo < hi) { int mid = (lo + hi) >> 1; if (batch[mid] < g) lo = mid + 1; else hi = mid; }
  gstart[g] = lo;
}

// 4 chunk-blocks per graph; 32 channel-quads x 8 row-streams; one atomic per channel per block.
__global__ __launch_bounds__(256) void k_pool(const unsigned short* __restrict__ Vb, const int* __restrict__ gstart,
                                              float* __restrict__ pooled) {
  int g = blockIdx.x >> 2, chunk = blockIdx.x & 3;
  int t = threadIdx.x;
  int c4 = t & 31, rs = t >> 5;
  int r0 = gstart[g], r1 = gstart[g + 1];
  float s0 = 0.f, s1 = 0.f, s2 = 0.f, s3 = 0.f;
  for (int r = r0 + chunk + 4 * rs + (c4 & 0) ; r < r1; r += 32) {
    uint2 p = *(const uint2*)(Vb + (size_t)r * 128 + c4 * 4);
    s0 += b2f(p.x & 0xffff); s1 += b2f(p.x >> 16);
    s2 += b2f(p.y & 0xffff); s3 += b2f(p.y >> 16);
  }
  __shared__ float sm[8][32][4];
  sm[rs][c4][0] = s0; sm[rs][c4][1] = s1; sm[rs][c4][2] = s2; sm[rs][c4][3] = s3;
  __syncthreads();
  if (t < 32) {
#pragma unroll
    for (int k = 0; k < 4; ++k) {
      float S = 0.f;
#pragma unroll
      for (int r = 0; r < 8; ++r) S += sm[r][t][k];
      atomicAdd(&pooled[g * 128 + t * 4 + k], S);
    }
  }
}

__global__ __launch_bounds__(256) void k_final(const float* __restrict__ pooled, const int* __restrict__ gstart,
                                               const float* __restrict__ Wl, const float* __restrict__ bl,
                                               const float* __restrict__ g4, const float* __restrict__ b4,
                                               float* __restrict__ out) {
  int t = threadIdx.x;
  int g = t >> 1, cls = t & 1;
  float cnt = fmaxf((float)(gstart[g + 1] - gstart[g]), 1.f);
  float inv = 1.f / cnt;
  float z = bl[cls];
  for (int f = 0; f < 128; ++f) {
    float ps = pooled[g * 128 + f];
    z += ps * inv * Wl[f * 2 + cls] + ps * Wl[(128 + f) * 2 + cls];
  }
  __shared__ float zs[256];
  __shared__ float st[4];
  zs[t] = z;
  __syncthreads();
  if (t < 2) {
    float s = 0.f, s2 = 0.f;
    for (int gg = 0; gg < 128; ++gg) { float v = zs[gg * 2 + t]; s += v; s2 += v * v; }
    float mean = s * (1.f / 128.f);
    float var = s2 * (1.f / 128.f) - mean * mean;
    var = fmaxf(var, 0.f);
    float sc = g4[t] * rsqrtf(var + 1e-5f);
    st[t] = sc; st[2 + t] = b4[t] - mean * sc;
  }
  __syncthreads();
  out[t] = zs[t] * st[cls] + st[2 + cls];
}

// ---------------- host launcher ----------------

extern "C" void kernel_launch(void* const* d_in, const int* in_sizes, int n_in,
                              void* d_out, int out_size, void* d_ws, size_t ws_size,
                              hipStream_t stream) {
  const float* x     = (const float*)d_in[0];
  const int*   ei    = (const int*)d_in[1];
  const int*   batch = (const int*)d_in[2];
  const float* W[3]    = {(const float*)d_in[3],  (const float*)d_in[9],  (const float*)d_in[15]};
  const float* asrc[3] = {(const float*)d_in[5],  (const float*)d_in[11], (const float*)d_in[17]};
  const float* adst[3] = {(const float*)d_in[6],  (const float*)d_in[12], (const float*)d_in[18]};
  const float* gam[3]  = {(const float*)d_in[7],  (const float*)d_in[13], (const float*)d_in[19]};
  const float* bet[3]  = {(const float*)d_in[8],  (const float*)d_in[14], (const float*)d_in[20]};
  const float* Wl    = (const float*)d_in[21];
  const float* bl    = (const float*)d_in[22];
  const float* g4    = (const float*)d_in[23];
  const float* beta4 = (const float*)d_in[24];

  char* ws = (char*)d_ws;
  size_t off = 0;
  auto alloc = [&](size_t bytes) -> void* {
    void* p = (void*)(ws + off);
    off += (bytes + 255) & ~(size_t)255;
    return p;
  };

  int* counts   = (int*)alloc((size_t)NN * 4);
  int* row_off  = (int*)alloc((size_t)(NN + 1) * 4);
  int* col      = (int*)alloc((size_t)NEP * 4);
  int* blk_tot  = (int*)alloc(256 * 4);
  int* blk_off  = (int*)alloc(256 * 4);
  int* cntmat   = (int*)alloc((size_t)NBLK * NBUK * 4);
  unsigned* pairs = (unsigned*)alloc((size_t)NEP * 4);
  unsigned short* Xb = (unsigned short*)alloc((size_t)NN * 128 * 2);   // GEMM input (bf16)
  unsigned short* Hb = (unsigned short*)alloc((size_t)NN * 128 * 2);   // GEMM output (bf16)
  unsigned short* Vb = (unsigned short*)alloc((size_t)NN * 128 * 2);   // agg output, pre-BN (bf16)
  unsigned short* Asb = (unsigned short*)alloc((size_t)NN * 16 * 2);
  float* Ad     = (float*)alloc((size_t)NN * 16 * 4);
  unsigned short* Wt0 = (unsigned short*)alloc(16384 * 2);
  unsigned short* Wt1 = (unsigned short*)alloc(16384 * 2);
  unsigned short* Wt2 = (unsigned short*)alloc(16384 * 2);
  const unsigned short* Wt[3] = {Wt0, Wt1, Wt2};
  float* partS  = (float*)alloc(128 * 128 * 4);
  float* partQ  = (float*)alloc(128 * 128 * 4);
  float* bn_sc  = (float*)alloc(256 * 4);
  float* pooled = (float*)alloc((size_t)NGRAPH * 128 * 4);
  int* gstart   = (int*)alloc((size_t)(NGRAPH + 1) * 4);

  // ---- CSR build: row_off (per-node) + bucketed scatter ----
  hipMemsetAsync(counts, 0, (size_t)NN * 4, stream);
  k_hist<<<(NEP + 255) / 256, 256, 0, stream>>>(ei, counts);
  k_scan1<<<(NN + 255) / 256, 256, 0, stream>>>(counts, row_off, blk_tot);
  k_scan2<<<1, 256, 0, stream>>>(blk_tot, blk_off, row_off, (NN + 255) / 256);
  k_scan3<<<(NN + 255) / 256, 256, 0, stream>>>(row_off, blk_off);

  k_bhist<<<NBLK, 256, 0, stream>>>(ei, cntmat);
  k_bscan<<<NBUK, 512, 0, stream>>>(cntmat);
  k_bscatter<<<NBLK, 256, 0, stream>>>(ei, cntmat, row_off, pairs);
  k_bfinal<<<NBUK, 256, 0, stream>>>(pairs, row_off, col);

  // weights -> bf16 transposed; x -> bf16; graph bounds
  k_wt<<<192, 256, 0, stream>>>(W[0], W[1], W[2], Wt0, Wt1, Wt2);
  k_cast<<<(NN * 16 + 255) / 256, 256, 0, stream>>>(x, Xb, NN * 16);
  k_gb<<<1, 256, 0, stream>>>(batch, gstart);

  hipMemsetAsync(pooled, 0, (size_t)NGRAPH * 128 * 4, stream);

  for (int L = 0; L < 3; ++L) {
    k_gemm<<<(NN + 127) / 128, 256, 0, stream>>>(Xb, Wt[L], Hb);
    k_coef<<<(NN * 16) / 256, 256, 0, stream>>>(Hb, asrc[L], adst[L], Asb, Ad);
    k_agg<<<NN / 8, 256, 0, stream>>>(Hb, Asb, Ad, row_off, col, Vb);
    k_bnreduce<<<128, 256, 0, stream>>>(Vb, partS, partQ);
    k_bnfin<<<1, 512, 0, stream>>>(partS, partQ, gam[L], bet[L], bn_sc);
    k_bnapply<<<(NN * 32) / 256, 256, 0, stream>>>(Vb, Xb, bn_sc);   // Xb = next layer input / pool input
  }

  k_pool<<<NGRAPH * 4, 256, 0, stream>>>(Xb, gstart, pooled);
  k_final<<<1, 256, 0, stream>>>(pooled, gstart, Wl, bl, g4, beta4, (float*)d_out);
}

// Round 8
// 311.120 us; speedup vs baseline: 1.6480x; 1.1232x over previous
//
#include <hip/hip_runtime.h>

#define NN 50000
#define NHEADS 16
#define NGRAPH 128
#define NEDGE 800000
#define NEP (NEDGE + NN)

// bucketed CSR build
#define EPB 2048
#define NBLK 416            // ceil(NEP / EPB)
#define NBUK 391            // ceil(NN / 128), bucket = dst >> 7
#define CASTB 3125          // NN*16/256
#define WTB 192

typedef float4 f4;
typedef __attribute__((ext_vector_type(4))) float f32x4;
typedef __attribute__((ext_vector_type(8))) short s8;   // 8 bf16 (4 VGPRs)

__device__ inline unsigned short f2b(float f) {
  union { float f; unsigned u; } v; v.f = f;
  unsigned r = v.u + 0x7FFFu + ((v.u >> 16) & 1u);   // RNE
  return (unsigned short)(r >> 16);
}
__device__ inline float b2f(unsigned u16) {          // low 16 bits = bf16
  union { unsigned u; float f; } v; v.u = u16 << 16;
  return v.f;
}

// ---------------- bucketed CSR build (no global per-node hist/scan) ----------------
// Bucket k = nodes [k*128, (k+1)*128). row_off derived bucket-locally in k_bfinal.

__global__ __launch_bounds__(256) void k_bhist(const int* __restrict__ ei, int* __restrict__ cntmat) {
  __shared__ int hist[NBUK];
  int t = threadIdx.x, b = blockIdx.x;
  for (int k = t; k < NBUK; k += 256) hist[k] = 0;
  __syncthreads();
  int i0 = b * EPB;
  int i1 = i0 + EPB < NEP ? i0 + EPB : NEP;
  for (int i = i0 + t; i < i1; i += 256) {
    int d = (i < NEDGE) ? ei[NEDGE + i] : (i - NEDGE);
    atomicAdd(&hist[d >> 7], 1);
  }
  __syncthreads();
  for (int k = t; k < NBUK; k += 256) cntmat[b * NBUK + k] = hist[k];
}

// per-bucket exclusive scan over blocks (in place) + bucket totals
__global__ __launch_bounds__(512) void k_bscan(int* __restrict__ cntmat, int* __restrict__ btotal) {
  __shared__ int buf[512];
  int t = threadIdx.x, k = blockIdx.x;
  int v = (t < NBLK) ? cntmat[t * NBUK + k] : 0;
  buf[t] = v;
  __syncthreads();
  for (int off = 1; off < 512; off <<= 1) {
    int y = (t >= off) ? buf[t - off] : 0;
    __syncthreads();
    buf[t] += y;
    __syncthreads();
  }
  if (t < NBLK) cntmat[t * NBUK + k] = buf[t] - v;
  if (t == 511) btotal[k] = buf[511];
}

// exclusive scan of bucket totals -> bucket bases
__global__ __launch_bounds__(512) void k_bbase(const int* __restrict__ btotal, int* __restrict__ bbase) {
  __shared__ int buf[512];
  int t = threadIdx.x;
  int v = (t < NBUK) ? btotal[t] : 0;
  buf[t] = v;
  __syncthreads();
  for (int off = 1; off < 512; off <<= 1) {
    int y = (t >= off) ? buf[t - off] : 0;
    __syncthreads();
    buf[t] += y;
    __syncthreads();
  }
  if (t < NBUK) bbase[t] = buf[t] - v;
  if (t == 511) bbase[NBUK] = buf[511];   // == NEP
}

__global__ __launch_bounds__(256) void k_bscatter(const int* __restrict__ ei, const int* __restrict__ cntmat,
                                                  const int* __restrict__ bbase, unsigned* __restrict__ pairs) {
  __shared__ int cur[NBUK];
  int t = threadIdx.x, b = blockIdx.x;
  for (int k = t; k < NBUK; k += 256) cur[k] = bbase[k] + cntmat[b * NBUK + k];
  __syncthreads();
  int i0 = b * EPB;
  int i1 = i0 + EPB < NEP ? i0 + EPB : NEP;
  for (int i = i0 + t; i < i1; i += 256) {
    int s, d;
    if (i < NEDGE) { s = ei[i]; d = ei[NEDGE + i]; }
    else { s = d = i - NEDGE; }
    int pos = atomicAdd(&cur[d >> 7], 1);
    pairs[pos] = ((unsigned)(d & 127) << 16) | (unsigned)s;   // src < 65536 fits 16 bits
  }
}

// per bucket: count 128 nodes, LDS-scan -> row_off, then scatter to exact CSR slots.
__global__ __launch_bounds__(256) void k_bfinal(const unsigned* __restrict__ pairs, const int* __restrict__ bbase,
                                                int* __restrict__ row_off, int* __restrict__ colp) {
  __shared__ int cnt[128];
  __shared__ int buf[128];
  __shared__ int cur[128];
  int t = threadIdx.x, k = blockIdx.x;
  int n0 = k << 7;
  if (t < 128) cnt[t] = 0;
  __syncthreads();
  int p0 = bbase[k], p1 = bbase[k + 1];
  for (int i = p0 + t; i < p1; i += 256) atomicAdd(&cnt[pairs[i] >> 16], 1);
  __syncthreads();
  if (t < 128) buf[t] = cnt[t];
  __syncthreads();
  for (int off = 1; off < 128; off <<= 1) {
    int y = (t < 128 && t >= off) ? buf[t - off] : 0;
    __syncthreads();
    if (t < 128) buf[t] += y;
    __syncthreads();
  }
  if (t < 128) {
    int excl = buf[t] - cnt[t];
    cur[t] = p0 + excl;
    if (n0 + t < NN) row_off[n0 + t] = p0 + excl;
  }
  if (k == NBUK - 1 && t == 0) row_off[NN] = p1;   // == NEP
  __syncthreads();
  for (int i = p0 + t; i < p1; i += 256) {
    unsigned r = pairs[i];
    int pos = atomicAdd(&cur[r >> 16], 1);
    colp[pos] = (int)(r & 0xffffu);
  }
}

// ---------------- fused prep: x->bf16 cast | W->W^T bf16 | graph bounds ----------------

__global__ __launch_bounds__(256) void k_prep(const float* __restrict__ X, unsigned short* __restrict__ Xb,
                                              const float* __restrict__ W0, const float* __restrict__ W1, const float* __restrict__ W2,
                                              unsigned short* __restrict__ T0, unsigned short* __restrict__ T1, unsigned short* __restrict__ T2,
                                              const int* __restrict__ batch, int* __restrict__ gstart) {
  int b = blockIdx.x, t = threadIdx.x;
  if (b < CASTB) {                       // cast: 8 elems per thread
    int i = b * 256 + t;
    const f4* X4 = (const f4*)X;
    f4 a = X4[2 * i], c = X4[2 * i + 1];
    uint4 o;
    o.x = (unsigned)f2b(a.x) | ((unsigned)f2b(a.y) << 16);
    o.y = (unsigned)f2b(a.z) | ((unsigned)f2b(a.w) << 16);
    o.z = (unsigned)f2b(c.x) | ((unsigned)f2b(c.y) << 16);
    o.w = (unsigned)f2b(c.z) | ((unsigned)f2b(c.w) << 16);
    ((uint4*)Xb)[i] = o;
  } else if (b < CASTB + WTB) {          // W transpose: 3 * 16384 elems
    int idx = (b - CASTB) * 256 + t;
    int L = idx >> 14, r = idx & 16383;
    int n = r >> 7, kk = r & 127;
    const float* W = (L == 0) ? W0 : (L == 1) ? W1 : W2;
    unsigned short* T = (L == 0) ? T0 : (L == 1) ? T1 : T2;
    T[n * 128 + kk] = f2b(W[kk * 128 + n]);
  } else {                               // graph bounds: lower_bound per g
    int g = t;
    if (g > NGRAPH) return;
    int lo = 0, hi = NN;
    while (lo < hi) { int mid = (lo + hi) >> 1; if (batch[mid] < g) lo = mid + 1; else hi = mid; }
    gstart[g] = lo;
  }
}

// ---------------- GEMM: Hb = bf16( Xb @ W )  via MFMA, no LDS ----------------

__global__ __launch_bounds__(256) void k_gemm(const unsigned short* __restrict__ Xb, const unsigned short* __restrict__ Wt,
                                              unsigned short* __restrict__ Hb) {
  int w = threadIdx.x >> 6, l = threadIdx.x & 63;
  int r0 = blockIdx.x * 128 + w * 32;          // this wave: rows r0..r0+31, all 128 cols
  int lr = l & 15, lg = l >> 4;
  f32x4 acc[2][8];
#pragma unroll
  for (int m = 0; m < 2; ++m)
#pragma unroll
    for (int n = 0; n < 8; ++n) acc[m][n] = (f32x4){0.f, 0.f, 0.f, 0.f};

#pragma unroll
  for (int ks = 0; ks < 4; ++ks) {
    int koff = ks * 32 + lg * 8;
    s8 a[2];
#pragma unroll
    for (int m = 0; m < 2; ++m) {
      int row = r0 + m * 16 + lr;
      row = (row < NN) ? row : (NN - 1);
      a[m] = *(const s8*)(Xb + (size_t)row * 128 + koff);
    }
    s8 b[8];
#pragma unroll
    for (int n = 0; n < 8; ++n)
      b[n] = *(const s8*)(Wt + (size_t)(n * 16 + lr) * 128 + koff);
#pragma unroll
    for (int m = 0; m < 2; ++m)
#pragma unroll
      for (int n = 0; n < 8; ++n)
        acc[m][n] = __builtin_amdgcn_mfma_f32_16x16x32_bf16(a[m], b[n], acc[m][n], 0, 0, 0);
  }

  // C/D layout: col = lane&15, row = (lane>>4)*4 + reg   [verified m89/m91]
#pragma unroll
  for (int m = 0; m < 2; ++m) {
    int rowb = r0 + m * 16 + lg * 4;
#pragma unroll
    for (int n = 0; n < 8; ++n) {
      int colb = n * 16 + lr;
#pragma unroll
      for (int reg = 0; reg < 4; ++reg) {
        int row = rowb + reg;
        if (row < NN) Hb[(size_t)row * 128 + colb] = f2b(acc[m][n][reg]);
      }
    }
  }
}

// ---------------- attention coefficients from bf16 H ----------------

__global__ __launch_bounds__(256) void k_coef(const unsigned short* __restrict__ Hb, const float* __restrict__ asrc,
                                              const float* __restrict__ adst, unsigned short* __restrict__ Asb, float* __restrict__ Ad) {
  int idx = blockIdx.x * 256 + threadIdx.x;
  if (idx >= NN * NHEADS) return;
  int n = idx >> 4, hd = idx & 15;
  uint4 hv = *(const uint4*)(Hb + (size_t)n * 128 + hd * 8);
  float h0 = b2f(hv.x & 0xffff), h1 = b2f(hv.x >> 16);
  float h2 = b2f(hv.y & 0xffff), h3 = b2f(hv.y >> 16);
  float h4 = b2f(hv.z & 0xffff), h5 = b2f(hv.z >> 16);
  float h6 = b2f(hv.w & 0xffff), h7 = b2f(hv.w >> 16);
  const f4* s4 = (const f4*)(asrc + hd * 8);
  const f4* d4 = (const f4*)(adst + hd * 8);
  f4 sa = s4[0], sb = s4[1], da = d4[0], db = d4[1];
  float as_v = h0 * sa.x + h1 * sa.y + h2 * sa.z + h3 * sa.w + h4 * sb.x + h5 * sb.y + h6 * sb.z + h7 * sb.w;
  float ad_v = h0 * da.x + h1 * da.y + h2 * da.z + h3 * da.w + h4 * db.x + h5 * db.y + h6 * db.z + h7 * db.w;
  Asb[idx] = f2b(as_v);
  Ad[idx] = ad_v;
}

// ---------------- aggregation: head-lane layout, 8-deep pipelined uint4 gathers ----------------
// 32 lanes per node: lane = (head h = l&15) x (edge parity = l>>4); 16 edges per node in flight.
// exp without max-shift: softmax shift-invariant, |e| bounded (~3) so no overflow.
// GAT bias dropped: following BN's mean subtraction absorbs per-channel constants exactly.

__global__ __launch_bounds__(256) void k_agg(const unsigned short* __restrict__ Hb, const unsigned short* __restrict__ Asb,
                                             const float* __restrict__ Ad,
                                             const int* __restrict__ row_off, const int* __restrict__ col,
                                             unsigned short* __restrict__ Vb) {
  int node = blockIdx.x * 8 + (threadIdx.x >> 5);   // 6250*8 == 50000 exactly
  int l = threadIdx.x & 31;
  int h = l & 15, par = l >> 4;
  int e0 = row_off[node], e1 = row_off[node + 1];
  float adh = Ad[node * 16 + h];
  float den = 0.f;
  float acc[8] = {0.f, 0.f, 0.f, 0.f, 0.f, 0.f, 0.f, 0.f};
  int j = e0 + par;
  for (; j + 14 < e1; j += 16) {   // 8 edges per lane in flight (16 per node)
    int s[8];
#pragma unroll
    for (int q = 0; q < 8; ++q) s[q] = col[j + 2 * q];
    float a[8];
#pragma unroll
    for (int q = 0; q < 8; ++q) a[q] = b2f(Asb[s[q] * 16 + h]);
    uint4 p[8];
#pragma unroll
    for (int q = 0; q < 8; ++q) p[q] = *(const uint4*)(Hb + (size_t)s[q] * 128 + h * 8);
#pragma unroll
    for (int q = 0; q < 8; ++q) {
      float e = a[q] + adh;
      e = (e > 0.f) ? e : 0.2f * e;
      a[q] = __expf(e);
      den += a[q];
    }
#pragma unroll
    for (int q = 0; q < 8; ++q) {
      acc[0] += a[q] * b2f(p[q].x & 0xffff); acc[1] += a[q] * b2f(p[q].x >> 16);
      acc[2] += a[q] * b2f(p[q].y & 0xffff); acc[3] += a[q] * b2f(p[q].y >> 16);
      acc[4] += a[q] * b2f(p[q].z & 0xffff); acc[5] += a[q] * b2f(p[q].z >> 16);
      acc[6] += a[q] * b2f(p[q].w & 0xffff); acc[7] += a[q] * b2f(p[q].w >> 16);
    }
  }
  for (; j + 6 < e1; j += 8) {     // 4-deep tail
    int s[4];
#pragma unroll
    for (int q = 0; q < 4; ++q) s[q] = col[j + 2 * q];
    float a[4];
#pragma unroll
    for (int q = 0; q < 4; ++q) a[q] = b2f(Asb[s[q] * 16 + h]);
    uint4 p[4];
#pragma unroll
    for (int q = 0; q < 4; ++q) p[q] = *(const uint4*)(Hb + (size_t)s[q] * 128 + h * 8);
#pragma unroll
    for (int q = 0; q < 4; ++q) {
      float e = a[q] + adh;
      e = (e > 0.f) ? e : 0.2f * e;
      a[q] = __expf(e);
      den += a[q];
    }
#pragma unroll
    for (int q = 0; q < 4; ++q) {
      acc[0] += a[q] * b2f(p[q].x & 0xffff); acc[1] += a[q] * b2f(p[q].x >> 16);
      acc[2] += a[q] * b2f(p[q].y & 0xffff); acc[3] += a[q] * b2f(p[q].y >> 16);
      acc[4] += a[q] * b2f(p[q].z & 0xffff); acc[5] += a[q] * b2f(p[q].z >> 16);
      acc[6] += a[q] * b2f(p[q].w & 0xffff); acc[7] += a[q] * b2f(p[q].w >> 16);
    }
  }
  for (; j < e1; j += 2) {
    int s0 = col[j];
    float a0 = b2f(Asb[s0 * 16 + h]) + adh;
    uint4 p0 = *(const uint4*)(Hb + (size_t)s0 * 128 + h * 8);
    a0 = (a0 > 0.f) ? a0 : 0.2f * a0;
    float x0 = __expf(a0);
    den += x0;
    acc[0] += x0 * b2f(p0.x & 0xffff);
    acc[1] += x0 * b2f(p0.x >> 16);
    acc[2] += x0 * b2f(p0.y & 0xffff);
    acc[3] += x0 * b2f(p0.y >> 16);
    acc[4] += x0 * b2f(p0.z & 0xffff);
    acc[5] += x0 * b2f(p0.z >> 16);
    acc[6] += x0 * b2f(p0.w & 0xffff);
    acc[7] += x0 * b2f(p0.w >> 16);
  }
  den += __shfl_xor(den, 16);
#pragma unroll
  for (int k = 0; k < 8; ++k) acc[k] += __shfl_xor(acc[k], 16);
  if (par == 0) {
    float inv = 1.f / (den + 1e-16f);
    uint4 o;
    o.x = (unsigned)f2b(acc[0] * inv) | ((unsigned)f2b(acc[1] * inv) << 16);
    o.y = (unsigned)f2b(acc[2] * inv) | ((unsigned)f2b(acc[3] * inv) << 16);
    o.z = (unsigned)f2b(acc[4] * inv) | ((unsigned)f2b(acc[5] * inv) << 16);
    o.w = (unsigned)f2b(acc[6] * inv) | ((unsigned)f2b(acc[7] * inv) << 16);
    *(uint4*)(Vb + (size_t)node * 128 + h * 8) = o;
  }
}

// ---------------- BatchNorm: atomic-free two-stage reduce over bf16 V ----------------

#define BN_CHUNK 391   // 128 * 391 = 50048 >= NN

__global__ __launch_bounds__(256) void k_bnreduce(const unsigned short* __restrict__ Vb, float* __restrict__ partS, float* __restrict__ partQ) {
  int t = threadIdx.x;
  int c4 = t & 31, rs = t >> 5;               // 32 channel-quads x 8 row-streams
  int r0 = blockIdx.x * BN_CHUNK + rs;
  int rend = blockIdx.x * BN_CHUNK + BN_CHUNK;
  if (rend > NN) rend = NN;
  float s0 = 0.f, s1 = 0.f, s2 = 0.f, s3 = 0.f;
  float q0 = 0.f, q1 = 0.f, q2 = 0.f, q3 = 0.f;
  for (int r = r0; r < rend; r += 8) {
    uint2 p = *(const uint2*)(Vb + (size_t)r * 128 + c4 * 4);
    float v0 = b2f(p.x & 0xffff), v1 = b2f(p.x >> 16);
    float v2 = b2f(p.y & 0xffff), v3 = b2f(p.y >> 16);
    s0 += v0; s1 += v1; s2 += v2; s3 += v3;
    q0 += v0 * v0; q1 += v1 * v1; q2 += v2 * v2; q3 += v3 * v3;
  }
  __shared__ float sm[8][32][8];
  sm[rs][c4][0] = s0; sm[rs][c4][1] = s1; sm[rs][c4][2] = s2; sm[rs][c4][3] = s3;
  sm[rs][c4][4] = q0; sm[rs][c4][5] = q1; sm[rs][c4][6] = q2; sm[rs][c4][7] = q3;
  __syncthreads();
  if (t < 32) {
#pragma unroll
    for (int k = 0; k < 4; ++k) {
      float S = 0.f, Q = 0.f;
#pragma unroll
      for (int r = 0; r < 8; ++r) { S += sm[r][t][k]; Q += sm[r][t][4 + k]; }
      partS[blockIdx.x * 128 + t * 4 + k] = S;
      partQ[blockIdx.x * 128 + t * 4 + k] = Q;
    }
  }
}

__global__ __launch_bounds__(512) void k_bnfin(const float* __restrict__ partS, const float* __restrict__ partQ,
                                               const float* __restrict__ gam, const float* __restrict__ bet,
                                               float* __restrict__ sc) {
  int t = threadIdx.x;
  int c = t & 127, q = (t >> 7) & 1, hf = t >> 8;
  const float* src = q ? partQ : partS;
  float s = 0.f;
#pragma unroll 8
  for (int i = hf * 64; i < hf * 64 + 64; ++i) s += src[i * 128 + c];
  __shared__ float sm[512];
  sm[t] = s;
  __syncthreads();
  if (t < 128) {
    float S = sm[t] + sm[t + 256];
    float Q = sm[t + 128] + sm[t + 384];
    float mean = S * (1.f / NN);
    float var = fmaxf(Q * (1.f / NN) - mean * mean, 0.f);
    float sg = gam[t] * rsqrtf(var + 1e-5f);
    sc[t] = sg;
    sc[128 + t] = bet[t] - mean * sg;
  }
}

__global__ __launch_bounds__(256) void k_bnapply(const unsigned short* __restrict__ Vb, unsigned short* __restrict__ Xb,
                                                 const float* __restrict__ sc) {
  int idx = blockIdx.x * 256 + threadIdx.x;   // quad index, total NN*32
  int c4 = idx & 31;
  uint2 p = ((const uint2*)Vb)[idx];
  f4 s = ((const f4*)sc)[c4], sh = ((const f4*)sc)[32 + c4];
  float v0 = fmaxf(b2f(p.x & 0xffff) * s.x + sh.x, 0.f);
  float v1 = fmaxf(b2f(p.x >> 16)    * s.y + sh.y, 0.f);
  float v2 = fmaxf(b2f(p.y & 0xffff) * s.z + sh.z, 0.f);
  float v3 = fmaxf(b2f(p.y >> 16)    * s.w + sh.w, 0.f);
  uint2 o;
  o.x = (unsigned)f2b(v0) | ((unsigned)f2b(v1) << 16);
  o.y = (unsigned)f2b(v2) | ((unsigned)f2b(v3) << 16);
  ((uint2*)Xb)[idx] = o;
}

// ---------------- pooling + final ----------------

__global__ __launch_bounds__(256) void k_pool(const unsigned short* __restrict__ Vb, const int* __restrict__ gstart,
                                              float* __restrict__ pooled) {
  int g = blockIdx.x >> 2, chunk = blockIdx.x & 3;
  int t = threadIdx.x;
  int c4 = t & 31, rs = t >> 5;
  int r0 = gstart[g], r1 = gstart[g + 1];
  float s0 = 0.f, s1 = 0.f, s2 = 0.f, s3 = 0.f;
  for (int r = r0 + chunk + 4 * rs; r < r1; r += 32) {
    uint2 p = *(const uint2*)(Vb + (size_t)r * 128 + c4 * 4);
    s0 += b2f(p.x & 0xffff); s1 += b2f(p.x >> 16);
    s2 += b2f(p.y & 0xffff); s3 += b2f(p.y >> 16);
  }
  __shared__ float sm[8][32][4];
  sm[rs][c4][0] = s0; sm[rs][c4][1] = s1; sm[rs][c4][2] = s2; sm[rs][c4][3] = s3;
  __syncthreads();
  if (t < 32) {
#pragma unroll
    for (int k = 0; k < 4; ++k) {
      float S = 0.f;
#pragma unroll
      for (int r = 0; r < 8; ++r) S += sm[r][t][k];
      atomicAdd(&pooled[g * 128 + t * 4 + k], S);
    }
  }
}

__global__ __launch_bounds__(256) void k_final(const float* __restrict__ pooled, const int* __restrict__ gstart,
                                               const float* __restrict__ Wl, const float* __restrict__ bl,
                                               const float* __restrict__ g4, const float* __restrict__ b4,
                                               float* __restrict__ out) {
  int t = threadIdx.x;
  int g = t >> 1, cls = t & 1;
  float cnt = fmaxf((float)(gstart[g + 1] - gstart[g]), 1.f);
  float inv = 1.f / cnt;
  float z = bl[cls];
  for (int f = 0; f < 128; ++f) {
    float ps = pooled[g * 128 + f];
    z += ps * inv * Wl[f * 2 + cls] + ps * Wl[(128 + f) * 2 + cls];
  }
  __shared__ float zs[256];
  __shared__ float st[4];
  zs[t] = z;
  __syncthreads();
  if (t < 2) {
    float s = 0.f, s2 = 0.f;
    for (int gg = 0; gg < 128; ++gg) { float v = zs[gg * 2 + t]; s += v; s2 += v * v; }
    float mean = s * (1.f / 128.f);
    float var = s2 * (1.f / 128.f) - mean * mean;
    var = fmaxf(var, 0.f);
    float sc = g4[t] * rsqrtf(var + 1e-5f);
    st[t] = sc; st[2 + t] = b4[t] - mean * sc;
  }
  __syncthreads();
  out[t] = zs[t] * st[cls] + st[2 + cls];
}

// ---------------- host launcher ----------------

extern "C" void kernel_launch(void* const* d_in, const int* in_sizes, int n_in,
                              void* d_out, int out_size, void* d_ws, size_t ws_size,
                              hipStream_t stream) {
  const float* x     = (const float*)d_in[0];
  const int*   ei    = (const int*)d_in[1];
  const int*   batch = (const int*)d_in[2];
  const float* W[3]    = {(const float*)d_in[3],  (const float*)d_in[9],  (const float*)d_in[15]};
  const float* asrc[3] = {(const float*)d_in[5],  (const float*)d_in[11], (const float*)d_in[17]};
  const float* adst[3] = {(const float*)d_in[6],  (const float*)d_in[12], (const float*)d_in[18]};
  const float* gam[3]  = {(const float*)d_in[7],  (const float*)d_in[13], (const float*)d_in[19]};
  const float* bet[3]  = {(const float*)d_in[8],  (const float*)d_in[14], (const float*)d_in[20]};
  const float* Wl    = (const float*)d_in[21];
  const float* bl    = (const float*)d_in[22];
  const float* g4    = (const float*)d_in[23];
  const float* beta4 = (const float*)d_in[24];

  char* ws = (char*)d_ws;
  size_t off = 0;
  auto alloc = [&](size_t bytes) -> void* {
    void* p = (void*)(ws + off);
    off += (bytes + 255) & ~(size_t)255;
    return p;
  };

  int* row_off  = (int*)alloc((size_t)(NN + 1) * 4);
  int* col      = (int*)alloc((size_t)NEP * 4);
  int* cntmat   = (int*)alloc((size_t)NBLK * NBUK * 4);
  int* btotal   = (int*)alloc((size_t)NBUK * 4);
  int* bbase    = (int*)alloc((size_t)(NBUK + 1) * 4);
  unsigned* pairs = (unsigned*)alloc((size_t)NEP * 4);
  unsigned short* Xb = (unsigned short*)alloc((size_t)NN * 128 * 2);   // GEMM input (bf16)
  unsigned short* Hb = (unsigned short*)alloc((size_t)NN * 128 * 2);   // GEMM output (bf16)
  unsigned short* Vb = (unsigned short*)alloc((size_t)NN * 128 * 2);   // agg output, pre-BN (bf16)
  unsigned short* Asb = (unsigned short*)alloc((size_t)NN * 16 * 2);
  float* Ad     = (float*)alloc((size_t)NN * 16 * 4);
  unsigned short* Wt0 = (unsigned short*)alloc(16384 * 2);
  unsigned short* Wt1 = (unsigned short*)alloc(16384 * 2);
  unsigned short* Wt2 = (unsigned short*)alloc(16384 * 2);
  const unsigned short* Wt[3] = {Wt0, Wt1, Wt2};
  float* partS  = (float*)alloc(128 * 128 * 4);
  float* partQ  = (float*)alloc(128 * 128 * 4);
  float* bn_sc  = (float*)alloc(256 * 4);
  float* pooled = (float*)alloc((size_t)NGRAPH * 128 * 4);
  int* gstart   = (int*)alloc((size_t)(NGRAPH + 1) * 4);

  // ---- CSR build: bucketed counting sort (row_off derived bucket-locally) ----
  k_bhist<<<NBLK, 256, 0, stream>>>(ei, cntmat);
  k_bscan<<<NBUK, 512, 0, stream>>>(cntmat, btotal);
  k_bbase<<<1, 512, 0, stream>>>(btotal, bbase);
  k_bscatter<<<NBLK, 256, 0, stream>>>(ei, cntmat, bbase, pairs);
  k_bfinal<<<NBUK, 256, 0, stream>>>(pairs, bbase, row_off, col);

  // fused prep: cast x, transpose weights, graph bounds
  k_prep<<<CASTB + WTB + 1, 256, 0, stream>>>(x, Xb, W[0], W[1], W[2], Wt0, Wt1, Wt2, batch, gstart);

  hipMemsetAsync(pooled, 0, (size_t)NGRAPH * 128 * 4, stream);

  for (int L = 0; L < 3; ++L) {
    k_gemm<<<(NN + 127) / 128, 256, 0, stream>>>(Xb, Wt[L], Hb);
    k_coef<<<(NN * 16) / 256, 256, 0, stream>>>(Hb, asrc[L], adst[L], Asb, Ad);
    k_agg<<<NN / 8, 256, 0, stream>>>(Hb, Asb, Ad, row_off, col, Vb);
    k_bnreduce<<<128, 256, 0, stream>>>(Vb, partS, partQ);
    k_bnfin<<<1, 512, 0, stream>>>(partS, partQ, gam[L], bet[L], bn_sc);
    k_bnapply<<<(NN * 32) / 256, 256, 0, stream>>>(Vb, Xb, bn_sc);   // Xb = next layer input / pool input
  }

  k_pool<<<NGRAPH * 4, 256, 0, stream>>>(Xb, gstart, pooled);
  k_final<<<1, 256, 0, stream>>>(pooled, gstart, Wl, bl, g4, beta4, (float*)d_out);
}

// Round 9
// 291.188 us; speedup vs baseline: 1.7608x; 1.0685x over previous
//
#include <hip/hip_runtime.h>

#define NN 50000
#define NHEADS 16
#define NGRAPH 128
#define NEDGE 800000
#define NEP (NEDGE + NN)

// bucketed CSR build
#define EPB 2048
#define NBLK 416            // ceil(NEP / EPB)
#define NBUK 391            // ceil(NN / 128), bucket = dst >> 7
#define CASTB 3125          // NN*16/256
#define WTB 192

typedef float4 f4;
typedef __attribute__((ext_vector_type(4))) float f32x4;
typedef __attribute__((ext_vector_type(8))) short s8;   // 8 bf16 (4 VGPRs)

__device__ inline unsigned short f2b(float f) {
  union { float f; unsigned u; } v; v.f = f;
  unsigned r = v.u + 0x7FFFu + ((v.u >> 16) & 1u);   // RNE
  return (unsigned short)(r >> 16);
}
__device__ inline float b2f(unsigned u16) {          // low 16 bits = bf16
  union { unsigned u; float f; } v; v.u = u16 << 16;
  return v.f;
}
__device__ inline float blo(unsigned u) {            // low bf16 of packed u32
  union { unsigned u; float f; } v; v.u = u << 16;
  return v.f;
}
__device__ inline float bhi(unsigned u) {            // high bf16 of packed u32
  union { unsigned u; float f; } v; v.u = u & 0xffff0000u;
  return v.f;
}

// ---------------- bucketed CSR build ----------------

__global__ __launch_bounds__(256) void k_bhist(const int* __restrict__ ei, int* __restrict__ cntmat) {
  __shared__ int hist[NBUK];
  int t = threadIdx.x, b = blockIdx.x;
  for (int k = t; k < NBUK; k += 256) hist[k] = 0;
  __syncthreads();
  int i0 = b * EPB;
  int i1 = i0 + EPB < NEP ? i0 + EPB : NEP;
  for (int i = i0 + t; i < i1; i += 256) {
    int d = (i < NEDGE) ? ei[NEDGE + i] : (i - NEDGE);
    atomicAdd(&hist[d >> 7], 1);
  }
  __syncthreads();
  for (int k = t; k < NBUK; k += 256) cntmat[b * NBUK + k] = hist[k];
}

__global__ __launch_bounds__(512) void k_bscan(int* __restrict__ cntmat, int* __restrict__ btotal) {
  __shared__ int buf[512];
  int t = threadIdx.x, k = blockIdx.x;
  int v = (t < NBLK) ? cntmat[t * NBUK + k] : 0;
  buf[t] = v;
  __syncthreads();
  for (int off = 1; off < 512; off <<= 1) {
    int y = (t >= off) ? buf[t - off] : 0;
    __syncthreads();
    buf[t] += y;
    __syncthreads();
  }
  if (t < NBLK) cntmat[t * NBUK + k] = buf[t] - v;
  if (t == 511) btotal[k] = buf[511];
}

__global__ __launch_bounds__(512) void k_bbase(const int* __restrict__ btotal, int* __restrict__ bbase) {
  __shared__ int buf[512];
  int t = threadIdx.x;
  int v = (t < NBUK) ? btotal[t] : 0;
  buf[t] = v;
  __syncthreads();
  for (int off = 1; off < 512; off <<= 1) {
    int y = (t >= off) ? buf[t - off] : 0;
    __syncthreads();
    buf[t] += y;
    __syncthreads();
  }
  if (t < NBUK) bbase[t] = buf[t] - v;
  if (t == 511) bbase[NBUK] = buf[511];   // == NEP
}

__global__ __launch_bounds__(256) void k_bscatter(const int* __restrict__ ei, const int* __restrict__ cntmat,
                                                  const int* __restrict__ bbase, unsigned* __restrict__ pairs) {
  __shared__ int cur[NBUK];
  int t = threadIdx.x, b = blockIdx.x;
  for (int k = t; k < NBUK; k += 256) cur[k] = bbase[k] + cntmat[b * NBUK + k];
  __syncthreads();
  int i0 = b * EPB;
  int i1 = i0 + EPB < NEP ? i0 + EPB : NEP;
  for (int i = i0 + t; i < i1; i += 256) {
    int s, d;
    if (i < NEDGE) { s = ei[i]; d = ei[NEDGE + i]; }
    else { s = d = i - NEDGE; }
    int pos = atomicAdd(&cur[d >> 7], 1);
    pairs[pos] = ((unsigned)(d & 127) << 16) | (unsigned)s;   // src < 65536 fits 16 bits
  }
}

__global__ __launch_bounds__(256) void k_bfinal(const unsigned* __restrict__ pairs, const int* __restrict__ bbase,
                                                int* __restrict__ row_off, int* __restrict__ colp) {
  __shared__ int cnt[128];
  __shared__ int buf[128];
  __shared__ int cur[128];
  int t = threadIdx.x, k = blockIdx.x;
  int n0 = k << 7;
  if (t < 128) cnt[t] = 0;
  __syncthreads();
  int p0 = bbase[k], p1 = bbase[k + 1];
  for (int i = p0 + t; i < p1; i += 256) atomicAdd(&cnt[pairs[i] >> 16], 1);
  __syncthreads();
  if (t < 128) buf[t] = cnt[t];
  __syncthreads();
  for (int off = 1; off < 128; off <<= 1) {
    int y = (t < 128 && t >= off) ? buf[t - off] : 0;
    __syncthreads();
    if (t < 128) buf[t] += y;
    __syncthreads();
  }
  if (t < 128) {
    int excl = buf[t] - cnt[t];
    cur[t] = p0 + excl;
    if (n0 + t < NN) row_off[n0 + t] = p0 + excl;
  }
  if (k == NBUK - 1 && t == 0) row_off[NN] = p1;   // == NEP
  __syncthreads();
  for (int i = p0 + t; i < p1; i += 256) {
    unsigned r = pairs[i];
    int pos = atomicAdd(&cur[r >> 16], 1);
    colp[pos] = (int)(r & 0xffffu);
  }
}

// ---------------- fused prep: x->bf16 cast | W->W^T bf16 | graph bounds ----------------

__global__ __launch_bounds__(256) void k_prep(const float* __restrict__ X, unsigned short* __restrict__ Xb,
                                              const float* __restrict__ W0, const float* __restrict__ W1, const float* __restrict__ W2,
                                              unsigned short* __restrict__ T0, unsigned short* __restrict__ T1, unsigned short* __restrict__ T2,
                                              const int* __restrict__ batch, int* __restrict__ gstart) {
  int b = blockIdx.x, t = threadIdx.x;
  if (b < CASTB) {                       // cast: 8 elems per thread
    int i = b * 256 + t;
    const f4* X4 = (const f4*)X;
    f4 a = X4[2 * i], c = X4[2 * i + 1];
    uint4 o;
    o.x = (unsigned)f2b(a.x) | ((unsigned)f2b(a.y) << 16);
    o.y = (unsigned)f2b(a.z) | ((unsigned)f2b(a.w) << 16);
    o.z = (unsigned)f2b(c.x) | ((unsigned)f2b(c.y) << 16);
    o.w = (unsigned)f2b(c.z) | ((unsigned)f2b(c.w) << 16);
    ((uint4*)Xb)[i] = o;
  } else if (b < CASTB + WTB) {          // W transpose: 3 * 16384 elems
    int idx = (b - CASTB) * 256 + t;
    int L = idx >> 14, r = idx & 16383;
    int n = r >> 7, kk = r & 127;
    const float* W = (L == 0) ? W0 : (L == 1) ? W1 : W2;
    unsigned short* T = (L == 0) ? T0 : (L == 1) ? T1 : T2;
    T[n * 128 + kk] = f2b(W[kk * 128 + n]);
  } else {                               // graph bounds: lower_bound per g
    int g = t;
    if (g > NGRAPH) return;
    int lo = 0, hi = NN;
    while (lo < hi) { int mid = (lo + hi) >> 1; if (batch[mid] < g) lo = mid + 1; else hi = mid; }
    gstart[g] = lo;
  }
}

// ---------------- GEMM: Hb = bf16( A @ W ), optional fused BN+ReLU on A ----------------
// FUSE=0: A = Xb (bf16, ready).  FUSE=1: A = BN(Vb)*relu via sc (scale[0..127], shift[128..255]).

template<int FUSE>
__global__ __launch_bounds__(256) void k_gemm_t(const unsigned short* __restrict__ A, const unsigned short* __restrict__ Wt,
                                                const float* __restrict__ sc, unsigned short* __restrict__ Hb) {
  int w = threadIdx.x >> 6, l = threadIdx.x & 63;
  int r0 = blockIdx.x * 128 + w * 32;          // this wave: rows r0..r0+31, all 128 cols
  int lr = l & 15, lg = l >> 4;
  f32x4 acc[2][8];
#pragma unroll
  for (int m = 0; m < 2; ++m)
#pragma unroll
    for (int n = 0; n < 8; ++n) acc[m][n] = (f32x4){0.f, 0.f, 0.f, 0.f};

#pragma unroll
  for (int ks = 0; ks < 4; ++ks) {
    int koff = ks * 32 + lg * 8;
    s8 a[2];
    if constexpr (FUSE) {
      f4 s0 = *(const f4*)(sc + koff),       s1 = *(const f4*)(sc + koff + 4);
      f4 h0 = *(const f4*)(sc + 128 + koff), h1 = *(const f4*)(sc + 128 + koff + 4);
#pragma unroll
      for (int m = 0; m < 2; ++m) {
        int row = r0 + m * 16 + lr;
        row = (row < NN) ? row : (NN - 1);
        uint4 raw = *(const uint4*)(A + (size_t)row * 128 + koff);
        float v0 = fmaxf(blo(raw.x) * s0.x + h0.x, 0.f);
        float v1 = fmaxf(bhi(raw.x) * s0.y + h0.y, 0.f);
        float v2 = fmaxf(blo(raw.y) * s0.z + h0.z, 0.f);
        float v3 = fmaxf(bhi(raw.y) * s0.w + h0.w, 0.f);
        float v4 = fmaxf(blo(raw.z) * s1.x + h1.x, 0.f);
        float v5 = fmaxf(bhi(raw.z) * s1.y + h1.y, 0.f);
        float v6 = fmaxf(blo(raw.w) * s1.z + h1.z, 0.f);
        float v7 = fmaxf(bhi(raw.w) * s1.w + h1.w, 0.f);
        union { s8 v; uint4 u; } pk;
        pk.u.x = (unsigned)f2b(v0) | ((unsigned)f2b(v1) << 16);
        pk.u.y = (unsigned)f2b(v2) | ((unsigned)f2b(v3) << 16);
        pk.u.z = (unsigned)f2b(v4) | ((unsigned)f2b(v5) << 16);
        pk.u.w = (unsigned)f2b(v6) | ((unsigned)f2b(v7) << 16);
        a[m] = pk.v;
      }
    } else {
#pragma unroll
      for (int m = 0; m < 2; ++m) {
        int row = r0 + m * 16 + lr;
        row = (row < NN) ? row : (NN - 1);
        a[m] = *(const s8*)(A + (size_t)row * 128 + koff);
      }
    }
    s8 b[8];
#pragma unroll
    for (int n = 0; n < 8; ++n)
      b[n] = *(const s8*)(Wt + (size_t)(n * 16 + lr) * 128 + koff);
#pragma unroll
    for (int m = 0; m < 2; ++m)
#pragma unroll
      for (int n = 0; n < 8; ++n)
        acc[m][n] = __builtin_amdgcn_mfma_f32_16x16x32_bf16(a[m], b[n], acc[m][n], 0, 0, 0);
  }

  // C/D layout: col = lane&15, row = (lane>>4)*4 + reg   [verified m89/m91]
#pragma unroll
  for (int m = 0; m < 2; ++m) {
    int rowb = r0 + m * 16 + lg * 4;
#pragma unroll
    for (int n = 0; n < 8; ++n) {
      int colb = n * 16 + lr;
#pragma unroll
      for (int reg = 0; reg < 4; ++reg) {
        int row = rowb + reg;
        if (row < NN) Hb[(size_t)row * 128 + colb] = f2b(acc[m][n][reg]);
      }
    }
  }
}

// ---------------- attention coefficients from bf16 H ----------------

__global__ __launch_bounds__(256) void k_coef(const unsigned short* __restrict__ Hb, const float* __restrict__ asrc,
                                              const float* __restrict__ adst, unsigned short* __restrict__ Asb, float* __restrict__ Ad) {
  int idx = blockIdx.x * 256 + threadIdx.x;
  if (idx >= NN * NHEADS) return;
  int n = idx >> 4, hd = idx & 15;
  uint4 hv = *(const uint4*)(Hb + (size_t)n * 128 + hd * 8);
  float h0 = blo(hv.x), h1 = bhi(hv.x);
  float h2 = blo(hv.y), h3 = bhi(hv.y);
  float h4 = blo(hv.z), h5 = bhi(hv.z);
  float h6 = blo(hv.w), h7 = bhi(hv.w);
  const f4* s4 = (const f4*)(asrc + hd * 8);
  const f4* d4 = (const f4*)(adst + hd * 8);
  f4 sa = s4[0], sb = s4[1], da = d4[0], db = d4[1];
  float as_v = h0 * sa.x + h1 * sa.y + h2 * sa.z + h3 * sa.w + h4 * sb.x + h5 * sb.y + h6 * sb.z + h7 * sb.w;
  float ad_v = h0 * da.x + h1 * da.y + h2 * da.z + h3 * da.w + h4 * db.x + h5 * db.y + h6 * db.z + h7 * db.w;
  Asb[idx] = f2b(as_v);
  Ad[idx] = ad_v;
}

// ---------------- aggregation: head-lane layout, true 8-deep pipelined uint4 gathers ----------------
// __launch_bounds__(256, 4): 128-VGPR budget so all 8 in-flight H loads stay live (R8's
// (256)-default capped at 44 VGPR and serialized the pipeline).

__global__ __launch_bounds__(256, 4) void k_agg(const unsigned short* __restrict__ Hb, const unsigned short* __restrict__ Asb,
                                                const float* __restrict__ Ad,
                                                const int* __restrict__ row_off, const int* __restrict__ col,
                                                unsigned short* __restrict__ Vb) {
  int node = blockIdx.x * 8 + (threadIdx.x >> 5);   // 6250*8 == 50000 exactly
  int l = threadIdx.x & 31;
  int h = l & 15, par = l >> 4;
  int e0 = row_off[node], e1 = row_off[node + 1];
  float adh = Ad[node * 16 + h];
  float den = 0.f;
  float acc[8] = {0.f, 0.f, 0.f, 0.f, 0.f, 0.f, 0.f, 0.f};
  int j = e0 + par;
  for (; j + 14 < e1; j += 16) {   // 8 edges per lane in flight (16 per node)
    int s[8];
#pragma unroll
    for (int q = 0; q < 8; ++q) s[q] = col[j + 2 * q];
    float a[8];
#pragma unroll
    for (int q = 0; q < 8; ++q) a[q] = b2f(Asb[s[q] * 16 + h]);
    uint4 p[8];
#pragma unroll
    for (int q = 0; q < 8; ++q) p[q] = *(const uint4*)(Hb + (size_t)s[q] * 128 + h * 8);
#pragma unroll
    for (int q = 0; q < 8; ++q) {
      float e = a[q] + adh;
      e = (e > 0.f) ? e : 0.2f * e;
      a[q] = __expf(e);
      den += a[q];
    }
#pragma unroll
    for (int q = 0; q < 8; ++q) {
      acc[0] += a[q] * blo(p[q].x); acc[1] += a[q] * bhi(p[q].x);
      acc[2] += a[q] * blo(p[q].y); acc[3] += a[q] * bhi(p[q].y);
      acc[4] += a[q] * blo(p[q].z); acc[5] += a[q] * bhi(p[q].z);
      acc[6] += a[q] * blo(p[q].w); acc[7] += a[q] * bhi(p[q].w);
    }
  }
  for (; j + 6 < e1; j += 8) {     // 4-deep tail
    int s[4];
#pragma unroll
    for (int q = 0; q < 4; ++q) s[q] = col[j + 2 * q];
    float a[4];
#pragma unroll
    for (int q = 0; q < 4; ++q) a[q] = b2f(Asb[s[q] * 16 + h]);
    uint4 p[4];
#pragma unroll
    for (int q = 0; q < 4; ++q) p[q] = *(const uint4*)(Hb + (size_t)s[q] * 128 + h * 8);
#pragma unroll
    for (int q = 0; q < 4; ++q) {
      float e = a[q] + adh;
      e = (e > 0.f) ? e : 0.2f * e;
      a[q] = __expf(e);
      den += a[q];
    }
#pragma unroll
    for (int q = 0; q < 4; ++q) {
      acc[0] += a[q] * blo(p[q].x); acc[1] += a[q] * bhi(p[q].x);
      acc[2] += a[q] * blo(p[q].y); acc[3] += a[q] * bhi(p[q].y);
      acc[4] += a[q] * blo(p[q].z); acc[5] += a[q] * bhi(p[q].z);
      acc[6] += a[q] * blo(p[q].w); acc[7] += a[q] * bhi(p[q].w);
    }
  }
  for (; j < e1; j += 2) {
    int s0 = col[j];
    float a0 = b2f(Asb[s0 * 16 + h]) + adh;
    uint4 p0 = *(const uint4*)(Hb + (size_t)s0 * 128 + h * 8);
    a0 = (a0 > 0.f) ? a0 : 0.2f * a0;
    float x0 = __expf(a0);
    den += x0;
    acc[0] += x0 * blo(p0.x); acc[1] += x0 * bhi(p0.x);
    acc[2] += x0 * blo(p0.y); acc[3] += x0 * bhi(p0.y);
    acc[4] += x0 * blo(p0.z); acc[5] += x0 * bhi(p0.z);
    acc[6] += x0 * blo(p0.w); acc[7] += x0 * bhi(p0.w);
  }
  den += __shfl_xor(den, 16);
#pragma unroll
  for (int k = 0; k < 8; ++k) acc[k] += __shfl_xor(acc[k], 16);
  if (par == 0) {
    float inv = 1.f / (den + 1e-16f);
    uint4 o;
    o.x = (unsigned)f2b(acc[0] * inv) | ((unsigned)f2b(acc[1] * inv) << 16);
    o.y = (unsigned)f2b(acc[2] * inv) | ((unsigned)f2b(acc[3] * inv) << 16);
    o.z = (unsigned)f2b(acc[4] * inv) | ((unsigned)f2b(acc[5] * inv) << 16);
    o.w = (unsigned)f2b(acc[6] * inv) | ((unsigned)f2b(acc[7] * inv) << 16);
    *(uint4*)(Vb + (size_t)node * 128 + h * 8) = o;
  }
}

// ---------------- BatchNorm stats: atomic-free two-stage reduce over bf16 V ----------------

#define BN_CHUNK 391   // 128 * 391 = 50048 >= NN

__global__ __launch_bounds__(256) void k_bnreduce(const unsigned short* __restrict__ Vb, float* __restrict__ partS, float* __restrict__ partQ) {
  int t = threadIdx.x;
  int c4 = t & 31, rs = t >> 5;               // 32 channel-quads x 8 row-streams
  int r0 = blockIdx.x * BN_CHUNK + rs;
  int rend = blockIdx.x * BN_CHUNK + BN_CHUNK;
  if (rend > NN) rend = NN;
  float s0 = 0.f, s1 = 0.f, s2 = 0.f, s3 = 0.f;
  float q0 = 0.f, q1 = 0.f, q2 = 0.f, q3 = 0.f;
  for (int r = r0; r < rend; r += 8) {
    uint2 p = *(const uint2*)(Vb + (size_t)r * 128 + c4 * 4);
    float v0 = blo(p.x), v1 = bhi(p.x);
    float v2 = blo(p.y), v3 = bhi(p.y);
    s0 += v0; s1 += v1; s2 += v2; s3 += v3;
    q0 += v0 * v0; q1 += v1 * v1; q2 += v2 * v2; q3 += v3 * v3;
  }
  __shared__ float sm[8][32][8];
  sm[rs][c4][0] = s0; sm[rs][c4][1] = s1; sm[rs][c4][2] = s2; sm[rs][c4][3] = s3;
  sm[rs][c4][4] = q0; sm[rs][c4][5] = q1; sm[rs][c4][6] = q2; sm[rs][c4][7] = q3;
  __syncthreads();
  if (t < 32) {
#pragma unroll
    for (int k = 0; k < 4; ++k) {
      float S = 0.f, Q = 0.f;
#pragma unroll
      for (int r = 0; r < 8; ++r) { S += sm[r][t][k]; Q += sm[r][t][4 + k]; }
      partS[blockIdx.x * 128 + t * 4 + k] = S;
      partQ[blockIdx.x * 128 + t * 4 + k] = Q;
    }
  }
}

__global__ __launch_bounds__(512) void k_bnfin(const float* __restrict__ partS, const float* __restrict__ partQ,
                                               const float* __restrict__ gam, const float* __restrict__ bet,
                                               float* __restrict__ sc) {
  int t = threadIdx.x;
  int c = t & 127, q = (t >> 7) & 1, hf = t >> 8;
  const float* src = q ? partQ : partS;
  float s = 0.f;
#pragma unroll 8
  for (int i = hf * 64; i < hf * 64 + 64; ++i) s += src[i * 128 + c];
  __shared__ float sm[512];
  sm[t] = s;
  __syncthreads();
  if (t < 128) {
    float S = sm[t] + sm[t + 256];
    float Q = sm[t + 128] + sm[t + 384];
    float mean = S * (1.f / NN);
    float var = fmaxf(Q * (1.f / NN) - mean * mean, 0.f);
    float sg = gam[t] * rsqrtf(var + 1e-5f);
    sc[t] = sg;
    sc[128 + t] = bet[t] - mean * sg;
  }
}

// ---------------- pooling (BN+ReLU applied inline) + final ----------------

__global__ __launch_bounds__(256) void k_pool(const unsigned short* __restrict__ Vb, const float* __restrict__ sc,
                                              const int* __restrict__ gstart, float* __restrict__ pooled) {
  int g = blockIdx.x >> 2, chunk = blockIdx.x & 3;
  int t = threadIdx.x;
  int c4 = t & 31, rs = t >> 5;
  f4 s = ((const f4*)sc)[c4], sh = ((const f4*)sc)[32 + c4];
  int r0 = gstart[g], r1 = gstart[g + 1];
  float s0 = 0.f, s1 = 0.f, s2 = 0.f, s3 = 0.f;
  for (int r = r0 + chunk + 4 * rs; r < r1; r += 32) {
    uint2 p = *(const uint2*)(Vb + (size_t)r * 128 + c4 * 4);
    s0 += fmaxf(blo(p.x) * s.x + sh.x, 0.f);
    s1 += fmaxf(bhi(p.x) * s.y + sh.y, 0.f);
    s2 += fmaxf(blo(p.y) * s.z + sh.z, 0.f);
    s3 += fmaxf(bhi(p.y) * s.w + sh.w, 0.f);
  }
  __shared__ float sm[8][32][4];
  sm[rs][c4][0] = s0; sm[rs][c4][1] = s1; sm[rs][c4][2] = s2; sm[rs][c4][3] = s3;
  __syncthreads();
  if (t < 32) {
#pragma unroll
    for (int k = 0; k < 4; ++k) {
      float S = 0.f;
#pragma unroll
      for (int r = 0; r < 8; ++r) S += sm[r][t][k];
      atomicAdd(&pooled[g * 128 + t * 4 + k], S);
    }
  }
}

__global__ __launch_bounds__(256) void k_final(const float* __restrict__ pooled, const int* __restrict__ gstart,
                                               const float* __restrict__ Wl, const float* __restrict__ bl,
                                               const float* __restrict__ g4, const float* __restrict__ b4,
                                               float* __restrict__ out) {
  int t = threadIdx.x;
  int g = t >> 1, cls = t & 1;
  float cnt = fmaxf((float)(gstart[g + 1] - gstart[g]), 1.f);
  float inv = 1.f / cnt;
  float z = bl[cls];
  for (int f = 0; f < 128; ++f) {
    float ps = pooled[g * 128 + f];
    z += ps * inv * Wl[f * 2 + cls] + ps * Wl[(128 + f) * 2 + cls];
  }
  __shared__ float zs[256];
  __shared__ float st[4];
  zs[t] = z;
  __syncthreads();
  if (t < 2) {
    float s = 0.f, s2 = 0.f;
    for (int gg = 0; gg < 128; ++gg) { float v = zs[gg * 2 + t]; s += v; s2 += v * v; }
    float mean = s * (1.f / 128.f);
    float var = s2 * (1.f / 128.f) - mean * mean;
    var = fmaxf(var, 0.f);
    float sc = g4[t] * rsqrtf(var + 1e-5f);
    st[t] = sc; st[2 + t] = b4[t] - mean * sc;
  }
  __syncthreads();
  out[t] = zs[t] * st[cls] + st[2 + cls];
}

// ---------------- host launcher ----------------

extern "C" void kernel_launch(void* const* d_in, const int* in_sizes, int n_in,
                              void* d_out, int out_size, void* d_ws, size_t ws_size,
                              hipStream_t stream) {
  const float* x     = (const float*)d_in[0];
  const int*   ei    = (const int*)d_in[1];
  const int*   batch = (const int*)d_in[2];
  const float* W[3]    = {(const float*)d_in[3],  (const float*)d_in[9],  (const float*)d_in[15]};
  const float* asrc[3] = {(const float*)d_in[5],  (const float*)d_in[11], (const float*)d_in[17]};
  const float* adst[3] = {(const float*)d_in[6],  (const float*)d_in[12], (const float*)d_in[18]};
  const float* gam[3]  = {(const float*)d_in[7],  (const float*)d_in[13], (const float*)d_in[19]};
  const float* bet[3]  = {(const float*)d_in[8],  (const float*)d_in[14], (const float*)d_in[20]};
  const float* Wl    = (const float*)d_in[21];
  const float* bl    = (const float*)d_in[22];
  const float* g4    = (const float*)d_in[23];
  const float* beta4 = (const float*)d_in[24];

  char* ws = (char*)d_ws;
  size_t off = 0;
  auto alloc = [&](size_t bytes) -> void* {
    void* p = (void*)(ws + off);
    off += (bytes + 255) & ~(size_t)255;
    return p;
  };

  int* row_off  = (int*)alloc((size_t)(NN + 1) * 4);
  int* col      = (int*)alloc((size_t)NEP * 4);
  int* cntmat   = (int*)alloc((size_t)NBLK * NBUK * 4);
  int* btotal   = (int*)alloc((size_t)NBUK * 4);
  int* bbase    = (int*)alloc((size_t)(NBUK + 1) * 4);
  unsigned* pairs = (unsigned*)alloc((size_t)NEP * 4);
  unsigned short* Xb = (unsigned short*)alloc((size_t)NN * 128 * 2);   // layer-0 GEMM input (bf16)
  unsigned short* Hb = (unsigned short*)alloc((size_t)NN * 128 * 2);   // GEMM output (bf16)
  unsigned short* Vb = (unsigned short*)alloc((size_t)NN * 128 * 2);   // agg output, pre-BN (bf16)
  unsigned short* Asb = (unsigned short*)alloc((size_t)NN * 16 * 2);
  float* Ad     = (float*)alloc((size_t)NN * 16 * 4);
  unsigned short* Wt0 = (unsigned short*)alloc(16384 * 2);
  unsigned short* Wt1 = (unsigned short*)alloc(16384 * 2);
  unsigned short* Wt2 = (unsigned short*)alloc(16384 * 2);
  const unsigned short* Wt[3] = {Wt0, Wt1, Wt2};
  float* partS  = (float*)alloc(128 * 128 * 4);
  float* partQ  = (float*)alloc(128 * 128 * 4);
  float* bn_sc  = (float*)alloc(256 * 4);
  float* pooled = (float*)alloc((size_t)NGRAPH * 128 * 4);
  int* gstart   = (int*)alloc((size_t)(NGRAPH + 1) * 4);

  // ---- CSR build: bucketed counting sort (row_off derived bucket-locally) ----
  k_bhist<<<NBLK, 256, 0, stream>>>(ei, cntmat);
  k_bscan<<<NBUK, 512, 0, stream>>>(cntmat, btotal);
  k_bbase<<<1, 512, 0, stream>>>(btotal, bbase);
  k_bscatter<<<NBLK, 256, 0, stream>>>(ei, cntmat, bbase, pairs);
  k_bfinal<<<NBUK, 256, 0, stream>>>(pairs, bbase, row_off, col);

  // fused prep: cast x, transpose weights, graph bounds
  k_prep<<<CASTB + WTB + 1, 256, 0, stream>>>(x, Xb, W[0], W[1], W[2], Wt0, Wt1, Wt2, batch, gstart);

  hipMemsetAsync(pooled, 0, (size_t)NGRAPH * 128 * 4, stream);

  for (int L = 0; L < 3; ++L) {
    if (L == 0)
      k_gemm_t<0><<<(NN + 127) / 128, 256, 0, stream>>>(Xb, Wt[L], nullptr, Hb);
    else
      k_gemm_t<1><<<(NN + 127) / 128, 256, 0, stream>>>(Vb, Wt[L], bn_sc, Hb);   // BN+ReLU fused on A
    k_coef<<<(NN * 16) / 256, 256, 0, stream>>>(Hb, asrc[L], adst[L], Asb, Ad);
    k_agg<<<NN / 8, 256, 0, stream>>>(Hb, Asb, Ad, row_off, col, Vb);
    k_bnreduce<<<128, 256, 0, stream>>>(Vb, partS, partQ);
    k_bnfin<<<1, 512, 0, stream>>>(partS, partQ, gam[L], bet[L], bn_sc);
  }

  k_pool<<<NGRAPH * 4, 256, 0, stream>>>(Vb, bn_sc, gstart, pooled);   // BN+ReLU fused
  k_final<<<1, 256, 0, stream>>>(pooled, gstart, Wl, bl, g4, beta4, (float*)d_out);
}